// Round 1
// baseline (3883.572 us; speedup 1.0000x reference)
//
#include <hip/hip_runtime.h>

// ---------------------------------------------------------------------------
// CoupledFEMSolver: assemble K_f, M_f (n x n) from fluid tets and
// K_s, M_s (3n x 3n) from solid tets.
//
// Geometry per tet (closed form, double precision to survive near-degenerate
// elements whose K entries ~ 1/det blow up to ~1e16):
//   r1 = p1-p0, r2 = p2-p0, r3 = p3-p0
//   det = r1 . (r2 x r3)            (signed; vol = |det|/6)
//   g1 = (r2 x r3)/det, g2 = (r3 x r1)/det, g3 = (r1 x r2)/det
//   g0 = -(g1+g2+g3)
// These are exactly inv([[1,p0],[1,p1],[1,p2],[1,p3]])[1:4,:] columns.
//
// Fluid:  K_e[a][b] = vol * (g_a . g_b);  M_e[a][b] = vol * (a==b ? .3 : .1)
// Solid:  K block (a,b) 3x3:
//   K[i][j] = vol*(lam*ga[i]*gb[j] + mu*ga[j]*gb[i] + (i==j)*mu*(ga.gb))
//   lam = coeff*nu, mu = coeff*(1-2nu)/2, coeff = E/((1+nu)(1-2nu))
//   M_s: diagonal only, rho*vol/4 at each of the 12 dofs.
// ---------------------------------------------------------------------------

__device__ __forceinline__ void tet_grads(const float* __restrict__ nodes,
                                          const int* ni,
                                          double g[4][3], double& vol,
                                          double& det_signed)
{
    double p[4][3];
#pragma unroll
    for (int a = 0; a < 4; ++a) {
        const float* q = nodes + 3ll * ni[a];
        p[a][0] = (double)q[0];
        p[a][1] = (double)q[1];
        p[a][2] = (double)q[2];
    }
    double r1[3], r2[3], r3[3];
#pragma unroll
    for (int k = 0; k < 3; ++k) {
        r1[k] = p[1][k] - p[0][k];
        r2[k] = p[2][k] - p[0][k];
        r3[k] = p[3][k] - p[0][k];
    }
    // c23 = r2 x r3 ; c31 = r3 x r1 ; c12 = r1 x r2
    double c23[3] = { r2[1]*r3[2] - r2[2]*r3[1],
                      r2[2]*r3[0] - r2[0]*r3[2],
                      r2[0]*r3[1] - r2[1]*r3[0] };
    double det = r1[0]*c23[0] + r1[1]*c23[1] + r1[2]*c23[2];
    double inv = 1.0 / det;
    double c31[3] = { r3[1]*r1[2] - r3[2]*r1[1],
                      r3[2]*r1[0] - r3[0]*r1[2],
                      r3[0]*r1[1] - r3[1]*r1[0] };
    double c12[3] = { r1[1]*r2[2] - r1[2]*r2[1],
                      r1[2]*r2[0] - r1[0]*r2[2],
                      r1[0]*r2[1] - r1[1]*r2[0] };
#pragma unroll
    for (int k = 0; k < 3; ++k) {
        g[1][k] = c23[k] * inv;
        g[2][k] = c31[k] * inv;
        g[3][k] = c12[k] * inv;
        g[0][k] = -(g[1][k] + g[2][k] + g[3][k]);
    }
    det_signed = det;
    vol = fabs(det) / 6.0;
}

__global__ void __launch_bounds__(256)
fluid_assemble(const float* __restrict__ nodes,
               const int* __restrict__ elems,
               float* __restrict__ Kf, float* __restrict__ Mf,
               int nelem, int n)
{
    int e = blockIdx.x * blockDim.x + threadIdx.x;
    if (e >= nelem) return;

    const int4 nd = *reinterpret_cast<const int4*>(elems + 4ll * e);
    int ni[4] = { nd.x, nd.y, nd.z, nd.w };

    double g[4][3], vol, det;
    tet_grads(nodes, ni, g, vol, det);

#pragma unroll
    for (int a = 0; a < 4; ++a) {
        long long rowoff = (long long)ni[a] * n;
#pragma unroll
        for (int b = 0; b < 4; ++b) {
            double kv = vol * (g[a][0]*g[b][0] + g[a][1]*g[b][1] + g[a][2]*g[b][2]);
            double mv = vol * (a == b ? 0.3 : 0.1);
            long long off = rowoff + ni[b];
            atomicAdd(Kf + off, (float)kv);
            atomicAdd(Mf + off, (float)mv);
        }
    }
}

__global__ void __launch_bounds__(256)
solid_assemble(const float* __restrict__ nodes,
               const int* __restrict__ elems,
               float* __restrict__ Ks, float* __restrict__ Ms,
               const float* __restrict__ E_p,
               const float* __restrict__ nu_p,
               const float* __restrict__ rho_p,
               int nelem, int n3)
{
    int e = blockIdx.x * blockDim.x + threadIdx.x;
    if (e >= nelem) return;

    double E   = (double)*E_p;
    double nu  = (double)*nu_p;
    double rho = (double)*rho_p;
    double coeff = E / ((1.0 + nu) * (1.0 - 2.0 * nu));
    double lam = coeff * nu;
    double mu  = coeff * (1.0 - 2.0 * nu) * 0.5;

    const int4 nd = *reinterpret_cast<const int4*>(elems + 4ll * e);
    int ni[4] = { nd.x, nd.y, nd.z, nd.w };

    double g[4][3], vol, det;
    tet_grads(nodes, ni, g, vol, det);

    double lv = lam * vol;
    double mv = mu * vol;

#pragma unroll
    for (int a = 0; a < 4; ++a) {
        long long row0 = 3ll * ni[a];
#pragma unroll
        for (int b = 0; b < 4; ++b) {
            long long col0 = 3ll * ni[b];
            double gg = g[a][0]*g[b][0] + g[a][1]*g[b][1] + g[a][2]*g[b][2];
#pragma unroll
            for (int i = 0; i < 3; ++i) {
                float* rowp = Ks + (row0 + i) * (long long)n3 + col0;
#pragma unroll
                for (int j = 0; j < 3; ++j) {
                    double val = lv * g[a][i] * g[b][j] + mv * g[a][j] * g[b][i];
                    if (i == j) val += mv * gg;
                    atomicAdd(rowp + j, (float)val);
                }
            }
        }
        // mass: diagonal only
        float mval = (float)(rho * vol * 0.25);
#pragma unroll
        for (int i = 0; i < 3; ++i) {
            long long d = row0 + i;
            atomicAdd(Ms + d * (long long)n3 + d, mval);
        }
    }
}

extern "C" void kernel_launch(void* const* d_in, const int* in_sizes, int n_in,
                              void* d_out, int out_size, void* d_ws, size_t ws_size,
                              hipStream_t stream)
{
    const float* nodes = (const float*)d_in[0];
    const int*   fe    = (const int*)d_in[1];
    const int*   se    = (const int*)d_in[2];
    const float* E_p   = (const float*)d_in[3];
    const float* nu_p  = (const float*)d_in[4];
    const float* rho_p = (const float*)d_in[5];

    const int n  = in_sizes[0] / 3;   // 2048
    const int nf = in_sizes[1] / 4;   // 400000
    const int ns = in_sizes[2] / 4;   // 400000
    const int n3 = 3 * n;             // 6144

    float* out = (float*)d_out;
    float* Kf = out;
    float* Mf = Kf + (long long)n * n;
    float* Ks = Mf + (long long)n * n;
    float* Ms = Ks + (long long)n3 * n3;

    // zero all four output matrices (graph-capturable memset node)
    hipMemsetAsync(d_out, 0, (size_t)out_size * sizeof(float), stream);

    const int bs = 256;
    fluid_assemble<<<(nf + bs - 1) / bs, bs, 0, stream>>>(nodes, fe, Kf, Mf, nf, n);
    solid_assemble<<<(ns + bs - 1) / bs, bs, 0, stream>>>(nodes, se, Ks, Ms,
                                                          E_p, nu_p, rho_p, ns, n3);
}

// Round 2
// 1056.535 us; speedup vs baseline: 3.6758x; 3.6758x over previous
//
#include <hip/hip_runtime.h>

// ---------------------------------------------------------------------------
// CoupledFEMSolver — gather-based assembly.
//
// K_f, M_f (n x n) from fluid tets; K_s, M_s (3n x 3n) from solid tets.
//
// Geometry per tet (closed form, double precision; K entries ~ 1/det can hit
// ~1e16 for near-degenerate tets):
//   r1 = p1-p0, r2 = p2-p0, r3 = p3-p0, det = r1.(r2 x r3)
//   g1 = (r2 x r3)/det, g2 = (r3 x r1)/det, g3 = (r1 x r2)/det, g0 = -(g1+g2+g3)
//   vol = |det|/6
//
// Fluid:  K_e[a][b] = vol*(g_a.g_b);  M_e[a][b] = vol*(a==b ? .3 : .1)
// Solid:  K block (a,b), entry (i,j):
//   vol*(lam*ga[i]*gb[j] + mu*ga[j]*gb[i] + (i==j)*mu*(ga.gb))
//   M_s diagonal only: rho*vol/4 per dof.
//
// Strategy: build node->(elem,local_a) inverted index, then one workgroup per
// output row accumulates the dense row in LDS (LDS atomics) and stores it
// once, coalesced. Eliminates the 57.6M random global atomics of round 0.
// ---------------------------------------------------------------------------

__device__ __forceinline__ void tet_grads(const float* __restrict__ nodes,
                                          const int* ni,
                                          double g[4][3], double& vol)
{
    double p[4][3];
#pragma unroll
    for (int a = 0; a < 4; ++a) {
        const float* q = nodes + 3ll * ni[a];
        p[a][0] = (double)q[0];
        p[a][1] = (double)q[1];
        p[a][2] = (double)q[2];
    }
    double r1[3], r2[3], r3[3];
#pragma unroll
    for (int k = 0; k < 3; ++k) {
        r1[k] = p[1][k] - p[0][k];
        r2[k] = p[2][k] - p[0][k];
        r3[k] = p[3][k] - p[0][k];
    }
    double c23[3] = { r2[1]*r3[2] - r2[2]*r3[1],
                      r2[2]*r3[0] - r2[0]*r3[2],
                      r2[0]*r3[1] - r2[1]*r3[0] };
    double det = r1[0]*c23[0] + r1[1]*c23[1] + r1[2]*c23[2];
    double inv = 1.0 / det;
    double c31[3] = { r3[1]*r1[2] - r3[2]*r1[1],
                      r3[2]*r1[0] - r3[0]*r1[2],
                      r3[0]*r1[1] - r3[1]*r1[0] };
    double c12[3] = { r1[1]*r2[2] - r1[2]*r2[1],
                      r1[2]*r2[0] - r1[0]*r2[2],
                      r1[0]*r2[1] - r1[1]*r2[0] };
#pragma unroll
    for (int k = 0; k < 3; ++k) {
        g[1][k] = c23[k] * inv;
        g[2][k] = c31[k] * inv;
        g[3][k] = c12[k] * inv;
        g[0][k] = -(g[1][k] + g[2][k] + g[3][k]);
    }
    vol = fabs(det) / 6.0;
}

// select among 4 values by runtime index (compiles to cndmask, no scratch)
__device__ __forceinline__ float sel4(float x0, float x1, float x2, float x3, int a) {
    float r = x0;
    r = (a == 1) ? x1 : r;
    r = (a == 2) ? x2 : r;
    r = (a == 3) ? x3 : r;
    return r;
}
__device__ __forceinline__ float sel3(float x0, float x1, float x2, int i) {
    float r = x0;
    r = (i == 1) ? x1 : r;
    r = (i == 2) ? x2 : r;
    return r;
}

// --------------------------- precompute geometry ---------------------------
// geom[e] = 4x float4: {g0x,g0y,g0z,g1x}, {g1y,g1z,g2x,g2y}, {g2z,g3x,g3y,g3z},
//                      {vol, 0,0,0}
__global__ void __launch_bounds__(256)
geom_kernel(const float* __restrict__ nodes, const int4* __restrict__ elems,
            float4* __restrict__ geom, int nelem)
{
    int e = blockIdx.x * blockDim.x + threadIdx.x;
    if (e >= nelem) return;
    int4 nd = elems[e];
    int ni[4] = { nd.x, nd.y, nd.z, nd.w };
    double g[4][3], vol;
    tet_grads(nodes, ni, g, vol);
    geom[e*4+0] = make_float4((float)g[0][0], (float)g[0][1], (float)g[0][2], (float)g[1][0]);
    geom[e*4+1] = make_float4((float)g[1][1], (float)g[1][2], (float)g[2][0], (float)g[2][1]);
    geom[e*4+2] = make_float4((float)g[2][2], (float)g[3][0], (float)g[3][1], (float)g[3][2]);
    geom[e*4+3] = make_float4((float)vol, 0.f, 0.f, 0.f);
}

// ------------------------------ inverted index ------------------------------
__global__ void __launch_bounds__(256)
hist_kernel(const int4* __restrict__ elems, int* __restrict__ cnt, int nelem, int n)
{
    extern __shared__ unsigned char smem[];
    int* h = (int*)smem;
    for (int i = threadIdx.x; i < n; i += blockDim.x) h[i] = 0;
    __syncthreads();
    for (int e = blockIdx.x * blockDim.x + threadIdx.x; e < nelem;
         e += gridDim.x * blockDim.x) {
        int4 nd = elems[e];
        atomicAdd(&h[nd.x], 1);
        atomicAdd(&h[nd.y], 1);
        atomicAdd(&h[nd.z], 1);
        atomicAdd(&h[nd.w], 1);
    }
    __syncthreads();
    for (int i = threadIdx.x; i < n; i += blockDim.x)
        if (h[i]) atomicAdd(&cnt[i], h[i]);
}

// exclusive scan of two count arrays (block 0 -> fluid, block 1 -> solid)
__global__ void __launch_bounds__(256)
scan_two(const int* __restrict__ cntF, const int* __restrict__ cntS,
         int* __restrict__ offF, int* __restrict__ offS,
         int* __restrict__ curF, int* __restrict__ curS, int n)
{
    const int* cnt = blockIdx.x ? cntS : cntF;
    int* off = blockIdx.x ? offS : offF;
    int* cur = blockIdx.x ? curS : curF;
    __shared__ int partial[256];
    int t = threadIdx.x;
    int ch = (n + 255) / 256;
    int base = t * ch;
    int s = 0;
    for (int k = 0; k < ch; ++k) {
        int i = base + k;
        if (i < n) s += cnt[i];
    }
    partial[t] = s;
    __syncthreads();
    for (int d = 1; d < 256; d <<= 1) {
        int v = (t >= d) ? partial[t - d] : 0;
        __syncthreads();
        partial[t] += v;
        __syncthreads();
    }
    int run = (t == 0) ? 0 : partial[t - 1];
    for (int k = 0; k < ch; ++k) {
        int i = base + k;
        if (i < n) { off[i] = run; cur[i] = run; run += cnt[i]; }
    }
    if (t == 255) off[n] = partial[255];
}

__global__ void __launch_bounds__(256)
scatter_kernel(const int4* __restrict__ elems, int* __restrict__ cur,
               int* __restrict__ entries, int nelem)
{
    int e = blockIdx.x * blockDim.x + threadIdx.x;
    if (e >= nelem) return;
    int4 nd = elems[e];
    int p;
    p = atomicAdd(&cur[nd.x], 1); entries[p] = e * 4 + 0;
    p = atomicAdd(&cur[nd.y], 1); entries[p] = e * 4 + 1;
    p = atomicAdd(&cur[nd.z], 1); entries[p] = e * 4 + 2;
    p = atomicAdd(&cur[nd.w], 1); entries[p] = e * 4 + 3;
}

// ------------------------------- fluid gather -------------------------------
// one block per node r: dense K row + M row in LDS, then coalesced store
__global__ void __launch_bounds__(256)
fluid_gather(const int* __restrict__ entries, const int* __restrict__ off,
             const int4* __restrict__ elems, const float4* __restrict__ geom,
             float* __restrict__ Kf, float* __restrict__ Mf, int n)
{
    extern __shared__ unsigned char smem[];
    float* Krow = (float*)smem;
    float* Mrow = Krow + n;
    for (int i = threadIdx.x; i < 2 * n; i += blockDim.x) Krow[i] = 0.f;
    __syncthreads();

    int r = blockIdx.x;
    int beg = off[r], end = off[r + 1];
    for (int idx = beg + threadIdx.x; idx < end; idx += blockDim.x) {
        int packed = entries[idx];
        int e = packed >> 2, a = packed & 3;
        int4 nd = elems[e];
        float4 q0 = geom[e*4+0], q1 = geom[e*4+1], q2 = geom[e*4+2], q3 = geom[e*4+3];
        const float g[12] = { q0.x,q0.y,q0.z, q0.w,q1.x,q1.y, q1.z,q1.w,q2.x, q2.y,q2.z,q2.w };
        float vol = q3.x;
        float gax = sel4(g[0], g[3], g[6], g[9],  a);
        float gay = sel4(g[1], g[4], g[7], g[10], a);
        float gaz = sel4(g[2], g[5], g[8], g[11], a);
        int cols[4] = { nd.x, nd.y, nd.z, nd.w };
#pragma unroll
        for (int b = 0; b < 4; ++b) {
            float kv = vol * (gax*g[b*3] + gay*g[b*3+1] + gaz*g[b*3+2]);
            float mv = vol * ((a == b) ? 0.3f : 0.1f);
            atomicAdd(&Krow[cols[b]], kv);
            atomicAdd(&Mrow[cols[b]], mv);
        }
    }
    __syncthreads();

    size_t rowoff = (size_t)r * n;
    int n4 = n >> 2;
    float4* K4 = (float4*)(Kf + rowoff);
    float4* M4 = (float4*)(Mf + rowoff);
    for (int i = threadIdx.x; i < n4; i += blockDim.x) {
        K4[i] = ((float4*)Krow)[i];
        M4[i] = ((float4*)Mrow)[i];
    }
    for (int i = (n4 << 2) + threadIdx.x; i < n; i += blockDim.x) {
        Kf[rowoff + i] = Krow[i];
        Mf[rowoff + i] = Mrow[i];
    }
}

// ------------------------------- solid gather -------------------------------
// one block per (node r, dof i): dense 3n-wide K_s row in LDS, plus vol sum
// for the diagonal M_s entry.
__global__ void __launch_bounds__(256)
solid_gather(const int* __restrict__ entries, const int* __restrict__ off,
             const int4* __restrict__ elems, const float4* __restrict__ geom,
             float* __restrict__ Ks, float* __restrict__ Ms,
             const float* __restrict__ E_p, const float* __restrict__ nu_p,
             const float* __restrict__ rho_p, int n3)
{
    extern __shared__ unsigned char smem[];
    float* row = (float*)smem;           // n3 floats
    float* volslot = row + n3;           // 1 float
    for (int k = threadIdx.x; k < n3; k += blockDim.x) row[k] = 0.f;
    if (threadIdx.x == 0) *volslot = 0.f;
    __syncthreads();

    int r = blockIdx.x / 3;
    int i = blockIdx.x - 3 * r;

    float E = *E_p, nu = *nu_p, rho = *rho_p;
    float coeff = E / ((1.f + nu) * (1.f - 2.f * nu));
    float lam = coeff * nu;
    float mu  = coeff * (1.f - 2.f * nu) * 0.5f;

    int beg = off[r], end = off[r + 1];
    float vsum = 0.f;
    for (int idx = beg + threadIdx.x; idx < end; idx += blockDim.x) {
        int packed = entries[idx];
        int e = packed >> 2, a = packed & 3;
        int4 nd = elems[e];
        float4 q0 = geom[e*4+0], q1 = geom[e*4+1], q2 = geom[e*4+2], q3 = geom[e*4+3];
        const float g[12] = { q0.x,q0.y,q0.z, q0.w,q1.x,q1.y, q1.z,q1.w,q2.x, q2.y,q2.z,q2.w };
        float vol = q3.x;
        vsum += vol;
        float gax = sel4(g[0], g[3], g[6], g[9],  a);
        float gay = sel4(g[1], g[4], g[7], g[10], a);
        float gaz = sel4(g[2], g[5], g[8], g[11], a);
        float gai = sel3(gax, gay, gaz, i);
        float ga[3] = { gax, gay, gaz };
        float lv = lam * vol, mv = mu * vol;
        int cols[4] = { nd.x, nd.y, nd.z, nd.w };
#pragma unroll
        for (int b = 0; b < 4; ++b) {
            float gb0 = g[b*3], gb1 = g[b*3+1], gb2 = g[b*3+2];
            float gg  = gax*gb0 + gay*gb1 + gaz*gb2;
            float gbi = sel3(gb0, gb1, gb2, i);
            int c0 = 3 * cols[b];
            float gbv[3] = { gb0, gb1, gb2 };
#pragma unroll
            for (int j = 0; j < 3; ++j) {
                float val = lv * gai * gbv[j] + mv * ga[j] * gbi;
                val = (i == j) ? val + mv * gg : val;
                atomicAdd(&row[c0 + j], val);
            }
        }
    }
    if (vsum != 0.f) atomicAdd(volslot, vsum);
    __syncthreads();

    size_t rowoff = (size_t)blockIdx.x * n3;
    int n34 = n3 >> 2;
    float4* K4 = (float4*)(Ks + rowoff);
    for (int k = threadIdx.x; k < n34; k += blockDim.x)
        K4[k] = ((float4*)row)[k];
    for (int k = (n34 << 2) + threadIdx.x; k < n3; k += blockDim.x)
        Ks[rowoff + k] = row[k];
    if (threadIdx.x == 0)
        Ms[(size_t)blockIdx.x * n3 + blockIdx.x] = rho * 0.25f * (*volslot);
}

// --------------------------- round-0 fallback path ---------------------------
__global__ void __launch_bounds__(256)
fluid_assemble(const float* __restrict__ nodes, const int* __restrict__ elems,
               float* __restrict__ Kf, float* __restrict__ Mf, int nelem, int n)
{
    int e = blockIdx.x * blockDim.x + threadIdx.x;
    if (e >= nelem) return;
    const int4 nd = *reinterpret_cast<const int4*>(elems + 4ll * e);
    int ni[4] = { nd.x, nd.y, nd.z, nd.w };
    double g[4][3], vol;
    tet_grads(nodes, ni, g, vol);
#pragma unroll
    for (int a = 0; a < 4; ++a) {
        long long rowoff = (long long)ni[a] * n;
#pragma unroll
        for (int b = 0; b < 4; ++b) {
            double kv = vol * (g[a][0]*g[b][0] + g[a][1]*g[b][1] + g[a][2]*g[b][2]);
            double mv = vol * (a == b ? 0.3 : 0.1);
            atomicAdd(Kf + rowoff + ni[b], (float)kv);
            atomicAdd(Mf + rowoff + ni[b], (float)mv);
        }
    }
}

__global__ void __launch_bounds__(256)
solid_assemble(const float* __restrict__ nodes, const int* __restrict__ elems,
               float* __restrict__ Ks, float* __restrict__ Ms,
               const float* __restrict__ E_p, const float* __restrict__ nu_p,
               const float* __restrict__ rho_p, int nelem, int n3)
{
    int e = blockIdx.x * blockDim.x + threadIdx.x;
    if (e >= nelem) return;
    double E = (double)*E_p, nu = (double)*nu_p, rho = (double)*rho_p;
    double coeff = E / ((1.0 + nu) * (1.0 - 2.0 * nu));
    double lam = coeff * nu, mu = coeff * (1.0 - 2.0 * nu) * 0.5;
    const int4 nd = *reinterpret_cast<const int4*>(elems + 4ll * e);
    int ni[4] = { nd.x, nd.y, nd.z, nd.w };
    double g[4][3], vol;
    tet_grads(nodes, ni, g, vol);
    double lv = lam * vol, mv = mu * vol;
#pragma unroll
    for (int a = 0; a < 4; ++a) {
        long long row0 = 3ll * ni[a];
#pragma unroll
        for (int b = 0; b < 4; ++b) {
            long long col0 = 3ll * ni[b];
            double gg = g[a][0]*g[b][0] + g[a][1]*g[b][1] + g[a][2]*g[b][2];
#pragma unroll
            for (int i = 0; i < 3; ++i) {
                float* rowp = Ks + (row0 + i) * (long long)n3 + col0;
#pragma unroll
                for (int j = 0; j < 3; ++j) {
                    double val = lv * g[a][i] * g[b][j] + mv * g[a][j] * g[b][i];
                    if (i == j) val += mv * gg;
                    atomicAdd(rowp + j, (float)val);
                }
            }
        }
        float mval = (float)(rho * vol * 0.25);
#pragma unroll
        for (int i = 0; i < 3; ++i) {
            long long d = row0 + i;
            atomicAdd(Ms + d * (long long)n3 + d, mval);
        }
    }
}

// ---------------------------------------------------------------------------
extern "C" void kernel_launch(void* const* d_in, const int* in_sizes, int n_in,
                              void* d_out, int out_size, void* d_ws, size_t ws_size,
                              hipStream_t stream)
{
    const float* nodes = (const float*)d_in[0];
    const int*   fe    = (const int*)d_in[1];
    const int*   se    = (const int*)d_in[2];
    const float* E_p   = (const float*)d_in[3];
    const float* nu_p  = (const float*)d_in[4];
    const float* rho_p = (const float*)d_in[5];

    const int n  = in_sizes[0] / 3;
    const int nf = in_sizes[1] / 4;
    const int ns = in_sizes[2] / 4;
    const int n3 = 3 * n;

    float* out = (float*)d_out;
    float* Kf = out;
    float* Mf = Kf + (size_t)n * n;
    float* Ks = Mf + (size_t)n * n;
    float* Ms = Ks + (size_t)n3 * n3;

    // workspace layout
    size_t pos = 0;
    auto take = [&](size_t bytes) {
        size_t p = pos;
        pos = (pos + bytes + 255) & ~(size_t)255;
        return p;
    };
    size_t geomF_o = take((size_t)nf * 64);
    size_t geomS_o = take((size_t)ns * 64);
    size_t entF_o  = take((size_t)4 * nf * 4);
    size_t entS_o  = take((size_t)4 * ns * 4);
    size_t ints_o  = take((size_t)(6 * n + 2) * 4);
    bool gather_ok = (pos <= ws_size);

    const int bs = 256;

    if (!gather_ok) {
        // fallback: round-0 scatter path
        hipMemsetAsync(d_out, 0, (size_t)out_size * sizeof(float), stream);
        fluid_assemble<<<(nf + bs - 1) / bs, bs, 0, stream>>>(nodes, fe, Kf, Mf, nf, n);
        solid_assemble<<<(ns + bs - 1) / bs, bs, 0, stream>>>(nodes, se, Ks, Ms,
                                                              E_p, nu_p, rho_p, ns, n3);
        return;
    }

    char* ws = (char*)d_ws;
    float4* geomF = (float4*)(ws + geomF_o);
    float4* geomS = (float4*)(ws + geomS_o);
    int* entF = (int*)(ws + entF_o);
    int* entS = (int*)(ws + entS_o);
    int* ib   = (int*)(ws + ints_o);
    int* cntF = ib;
    int* cntS = ib + n;
    int* offF = ib + 2 * n;
    int* offS = ib + 3 * n + 1;
    int* curF = ib + 4 * n + 2;
    int* curS = ib + 5 * n + 2;

    const int4* fe4 = (const int4*)fe;
    const int4* se4 = (const int4*)se;

    // zero counters
    hipMemsetAsync(cntF, 0, (size_t)2 * n * sizeof(int), stream);
    // zero M_s region (diagonal written later; rest must be 0)
    hipMemsetAsync(Ms, 0, (size_t)n3 * n3 * sizeof(float), stream);

    // per-element geometry
    geom_kernel<<<(nf + bs - 1) / bs, bs, 0, stream>>>(nodes, fe4, geomF, nf);
    geom_kernel<<<(ns + bs - 1) / bs, bs, 0, stream>>>(nodes, se4, geomS, ns);

    // inverted index
    hist_kernel<<<256, bs, n * sizeof(int), stream>>>(fe4, cntF, nf, n);
    hist_kernel<<<256, bs, n * sizeof(int), stream>>>(se4, cntS, ns, n);
    scan_two<<<2, bs, 0, stream>>>(cntF, cntS, offF, offS, curF, curS, n);
    scatter_kernel<<<(nf + bs - 1) / bs, bs, 0, stream>>>(fe4, curF, entF, nf);
    scatter_kernel<<<(ns + bs - 1) / bs, bs, 0, stream>>>(se4, curS, entS, ns);

    // gather-assemble rows
    fluid_gather<<<n, bs, (size_t)2 * n * sizeof(float), stream>>>(
        entF, offF, fe4, geomF, Kf, Mf, n);
    solid_gather<<<n3, bs, (size_t)(n3 + 1) * sizeof(float), stream>>>(
        entS, offS, se4, geomS, Ks, Ms, E_p, nu_p, rho_p, n3);
}

// Round 3
// 579.296 us; speedup vs baseline: 6.7039x; 1.8238x over previous
//
#include <hip/hip_runtime.h>

// ---------------------------------------------------------------------------
// CoupledFEMSolver — gather assembly with counting-sort inverted index.
//
// K_f, M_f (n x n) from fluid tets; K_s, M_s (3n x 3n) from solid tets.
//
// Geometry per tet (double precision; K entries ~ 1/det reach ~1e14):
//   det = r1.(r2 x r3); g1=(r2xr3)/det, g2=(r3xr1)/det, g3=(r1xr2)/det,
//   g0=-(g1+g2+g3); vol=|det|/6
// Fluid:  K_e[a][b] = vol*(ga.gb); M_e[a][b] = vol*(a==b ? .3 : .1)
// Solid:  K block (a,b) entry (i,j) =
//   vol*(lam*ga_i*gb_j + mu*ga_j*gb_i + (i==j)*mu*(ga.gb));
//   M_s diagonal only: rho*vol/4 per dof.
//
// Pipeline:
//   geom_rec     : per element, 64B record {g1,g2,g3,vol,nd0..3}
//   hist_part    : per-partition node histogram  -> H[b][node]   (coalesced)
//   colscan      : per-node prefix over partitions, totals -> cnt
//   scan_two     : exclusive scan of cnt -> off
//   scatter_part : place (elem,a) entries at off[node]+base+LDS cursor
//   fluid_gather : block per node row; dense LDS row; coalesced store
//   solid_gather : block per (node,i) row, XCD-swizzled so the 3 i-blocks of
//                  a node share an XCD L2; dense LDS row; coalesced store
// ---------------------------------------------------------------------------

#define G_PART 256

__device__ __forceinline__ void tet_grads(const float* __restrict__ nodes,
                                          const int* ni,
                                          double g[4][3], double& vol)
{
    double p[4][3];
#pragma unroll
    for (int a = 0; a < 4; ++a) {
        const float* q = nodes + 3ll * ni[a];
        p[a][0] = (double)q[0];
        p[a][1] = (double)q[1];
        p[a][2] = (double)q[2];
    }
    double r1[3], r2[3], r3[3];
#pragma unroll
    for (int k = 0; k < 3; ++k) {
        r1[k] = p[1][k] - p[0][k];
        r2[k] = p[2][k] - p[0][k];
        r3[k] = p[3][k] - p[0][k];
    }
    double c23[3] = { r2[1]*r3[2] - r2[2]*r3[1],
                      r2[2]*r3[0] - r2[0]*r3[2],
                      r2[0]*r3[1] - r2[1]*r3[0] };
    double det = r1[0]*c23[0] + r1[1]*c23[1] + r1[2]*c23[2];
    double inv = 1.0 / det;
    double c31[3] = { r3[1]*r1[2] - r3[2]*r1[1],
                      r3[2]*r1[0] - r3[0]*r1[2],
                      r3[0]*r1[1] - r3[1]*r1[0] };
    double c12[3] = { r1[1]*r2[2] - r1[2]*r2[1],
                      r1[2]*r2[0] - r1[0]*r2[2],
                      r1[0]*r2[1] - r1[1]*r2[0] };
#pragma unroll
    for (int k = 0; k < 3; ++k) {
        g[1][k] = c23[k] * inv;
        g[2][k] = c31[k] * inv;
        g[3][k] = c12[k] * inv;
        g[0][k] = -(g[1][k] + g[2][k] + g[3][k]);
    }
    vol = fabs(det) / 6.0;
}

__device__ __forceinline__ float sel4(float x0, float x1, float x2, float x3, int a) {
    float r = x0;
    r = (a == 1) ? x1 : r;
    r = (a == 2) ? x2 : r;
    r = (a == 3) ? x3 : r;
    return r;
}
__device__ __forceinline__ float sel3(float x0, float x1, float x2, int i) {
    float r = x0;
    r = (i == 1) ? x1 : r;
    r = (i == 2) ? x2 : r;
    return r;
}

// ------------------------- element records (64 B) ---------------------------
// q0=(g1x,g1y,g1z,g2x) q1=(g2y,g2z,g3x,g3y) q2=(g3z,vol,ndx,ndy) q3=(ndz,ndw,-,-)
__global__ void __launch_bounds__(256)
geom_rec(const float* __restrict__ nodes, const int4* __restrict__ elems,
         float4* __restrict__ rec, int nelem)
{
    int e = blockIdx.x * blockDim.x + threadIdx.x;
    if (e >= nelem) return;
    int4 nd = elems[e];
    int ni[4] = { nd.x, nd.y, nd.z, nd.w };
    double g[4][3], vol;
    tet_grads(nodes, ni, g, vol);
    rec[e*4+0] = make_float4((float)g[1][0], (float)g[1][1], (float)g[1][2], (float)g[2][0]);
    rec[e*4+1] = make_float4((float)g[2][1], (float)g[2][2], (float)g[3][0], (float)g[3][1]);
    rec[e*4+2] = make_float4((float)g[3][2], (float)vol,
                             __int_as_float(nd.x), __int_as_float(nd.y));
    rec[e*4+3] = make_float4(__int_as_float(nd.z), __int_as_float(nd.w), 0.f, 0.f);
}

#define UNPACK_REC(rec_, e_)                                                  \
    float4 q0 = (rec_)[(e_)*4+0], q1 = (rec_)[(e_)*4+1],                      \
           q2 = (rec_)[(e_)*4+2], q3 = (rec_)[(e_)*4+3];                      \
    const float gx[4] = { -(q0.x+q0.w+q1.z), q0.x, q0.w, q1.z };              \
    const float gy[4] = { -(q0.y+q1.x+q1.w), q0.y, q1.x, q1.w };              \
    const float gz[4] = { -(q0.z+q1.y+q2.x), q0.z, q1.y, q2.x };              \
    float vol = q2.y;                                                         \
    const int cols[4] = { __float_as_int(q2.z), __float_as_int(q2.w),         \
                          __float_as_int(q3.x), __float_as_int(q3.y) };

// --------------------- counting-sort inverted index -------------------------
// H layout: [G_PART][n]  (partition-major: all three passes coalesced)
__global__ void __launch_bounds__(256)
hist_part(const int4* __restrict__ elems, int* __restrict__ H,
          int nelem, int n, int chunk)
{
    extern __shared__ int h[];
    for (int i = threadIdx.x; i < n; i += blockDim.x) h[i] = 0;
    __syncthreads();
    int b = blockIdx.x;
    int beg = b * chunk, end = min(nelem, beg + chunk);
    for (int e = beg + threadIdx.x; e < end; e += blockDim.x) {
        int4 nd = elems[e];
        atomicAdd(&h[nd.x], 1);
        atomicAdd(&h[nd.y], 1);
        atomicAdd(&h[nd.z], 1);
        atomicAdd(&h[nd.w], 1);
    }
    __syncthreads();
    int* Hb = H + (size_t)b * n;
    for (int i = threadIdx.x; i < n; i += blockDim.x) Hb[i] = h[i];
}

// thread per node: exclusive prefix over partitions (in place), total -> cnt
__global__ void __launch_bounds__(256)
colscan(int* __restrict__ H, int* __restrict__ cnt, int n)
{
    int node = blockIdx.x * blockDim.x + threadIdx.x;
    if (node >= n) return;
    int s = 0;
    for (int b = 0; b < G_PART; ++b) {
        size_t idx = (size_t)b * n + node;
        int v = H[idx];
        H[idx] = s;
        s += v;
    }
    cnt[node] = s;
}

// exclusive scan of two count arrays (block 0 -> fluid, block 1 -> solid)
__global__ void __launch_bounds__(256)
scan_two(const int* __restrict__ cntF, const int* __restrict__ cntS,
         int* __restrict__ offF, int* __restrict__ offS, int n)
{
    const int* cnt = blockIdx.x ? cntS : cntF;
    int* off = blockIdx.x ? offS : offF;
    __shared__ int partial[256];
    int t = threadIdx.x;
    int ch = (n + 255) / 256;
    int base = t * ch;
    int s = 0;
    for (int k = 0; k < ch; ++k) {
        int i = base + k;
        if (i < n) s += cnt[i];
    }
    partial[t] = s;
    __syncthreads();
    for (int d = 1; d < 256; d <<= 1) {
        int v = (t >= d) ? partial[t - d] : 0;
        __syncthreads();
        partial[t] += v;
        __syncthreads();
    }
    int run = (t == 0) ? 0 : partial[t - 1];
    for (int k = 0; k < ch; ++k) {
        int i = base + k;
        if (i < n) { off[i] = run; run += cnt[i]; }
    }
    if (t == 255) off[n] = partial[255];
}

__global__ void __launch_bounds__(256)
scatter_part(const int4* __restrict__ elems, const int* __restrict__ H,
             const int* __restrict__ off, int* __restrict__ entries,
             int nelem, int n, int chunk)
{
    extern __shared__ int slot[];
    int b = blockIdx.x;
    const int* Hb = H + (size_t)b * n;
    for (int i = threadIdx.x; i < n; i += blockDim.x)
        slot[i] = off[i] + Hb[i];
    __syncthreads();
    int beg = b * chunk, end = min(nelem, beg + chunk);
    for (int e = beg + threadIdx.x; e < end; e += blockDim.x) {
        int4 nd = elems[e];
        int p;
        p = atomicAdd(&slot[nd.x], 1); entries[p] = e * 4 + 0;
        p = atomicAdd(&slot[nd.y], 1); entries[p] = e * 4 + 1;
        p = atomicAdd(&slot[nd.z], 1); entries[p] = e * 4 + 2;
        p = atomicAdd(&slot[nd.w], 1); entries[p] = e * 4 + 3;
    }
}

// ------------------------------- fluid gather -------------------------------
__global__ void __launch_bounds__(256)
fluid_gather(const int* __restrict__ entries, const int* __restrict__ off,
             const float4* __restrict__ rec,
             float* __restrict__ Kf, float* __restrict__ Mf, int n)
{
    extern __shared__ unsigned char smem[];
    float* Krow = (float*)smem;
    float* Mrow = Krow + n;
    for (int i = threadIdx.x; i < 2 * n; i += blockDim.x) Krow[i] = 0.f;
    __syncthreads();

    int r = blockIdx.x;
    int beg = off[r], end = off[r + 1];
    for (int idx = beg + threadIdx.x; idx < end; idx += blockDim.x) {
        int packed = entries[idx];
        int e = packed >> 2, a = packed & 3;
        UNPACK_REC(rec, e);
        float gax = sel4(gx[0], gx[1], gx[2], gx[3], a);
        float gay = sel4(gy[0], gy[1], gy[2], gy[3], a);
        float gaz = sel4(gz[0], gz[1], gz[2], gz[3], a);
#pragma unroll
        for (int b = 0; b < 4; ++b) {
            float kv = vol * (gax*gx[b] + gay*gy[b] + gaz*gz[b]);
            float mv = vol * ((a == b) ? 0.3f : 0.1f);
            atomicAdd(&Krow[cols[b]], kv);
            atomicAdd(&Mrow[cols[b]], mv);
        }
    }
    __syncthreads();

    size_t rowoff = (size_t)r * n;
    int n4 = n >> 2;
    float4* K4 = (float4*)(Kf + rowoff);
    float4* M4 = (float4*)(Mf + rowoff);
    for (int i = threadIdx.x; i < n4; i += blockDim.x) {
        K4[i] = ((float4*)Krow)[i];
        M4[i] = ((float4*)Mrow)[i];
    }
    for (int i = (n4 << 2) + threadIdx.x; i < n; i += blockDim.x) {
        Kf[rowoff + i] = Krow[i];
        Mf[rowoff + i] = Mrow[i];
    }
}

// ------------------------------- solid gather -------------------------------
// block -> (node r, dof ii); swizzled so the 3 ii-blocks of a node share an
// XCD (bid % 8) and are adjacent in dispatch order -> record reads hit L2.
__global__ void __launch_bounds__(256)
solid_gather(const int* __restrict__ entries, const int* __restrict__ off,
             const float4* __restrict__ rec,
             float* __restrict__ Ks, float* __restrict__ Ms,
             const float* __restrict__ E_p, const float* __restrict__ nu_p,
             const float* __restrict__ rho_p, int n, int n3)
{
    extern __shared__ unsigned char smem[];
    float* row = (float*)smem;           // n3 floats
    float* volslot = row + n3;
    for (int k = threadIdx.x; k < n3; k += blockDim.x) row[k] = 0.f;
    if (threadIdx.x == 0) *volslot = 0.f;
    __syncthreads();

    int bid = blockIdx.x;
    int r, ii;
    if ((n & 7) == 0) {
        int x = bid & 7;          // target XCD
        int q = bid >> 3;         // 0 .. 3n/8-1
        ii = q % 3;
        int rr = q / 3;           // 0 .. n/8-1
        r = rr * 8 + x;
    } else {
        r = bid / 3;
        ii = bid - 3 * r;
    }
    int rowIdx = 3 * r + ii;

    float E = *E_p, nu = *nu_p, rho = *rho_p;
    float coeff = E / ((1.f + nu) * (1.f - 2.f * nu));
    float lam = coeff * nu;
    float mu  = coeff * (1.f - 2.f * nu) * 0.5f;

    int beg = off[r], end = off[r + 1];
    float vsum = 0.f;
    for (int idx = beg + threadIdx.x; idx < end; idx += blockDim.x) {
        int packed = entries[idx];
        int e = packed >> 2, a = packed & 3;
        UNPACK_REC(rec, e);
        vsum += vol;
        float gax = sel4(gx[0], gx[1], gx[2], gx[3], a);
        float gay = sel4(gy[0], gy[1], gy[2], gy[3], a);
        float gaz = sel4(gz[0], gz[1], gz[2], gz[3], a);
        float gai = sel3(gax, gay, gaz, ii);
        const float ga[3] = { gax, gay, gaz };
        float lv = lam * vol, mv = mu * vol;
#pragma unroll
        for (int b = 0; b < 4; ++b) {
            float gb0 = gx[b], gb1 = gy[b], gb2 = gz[b];
            float gg  = gax*gb0 + gay*gb1 + gaz*gb2;
            float gbi = sel3(gb0, gb1, gb2, ii);
            const float gbv[3] = { gb0, gb1, gb2 };
            int c0 = 3 * cols[b];
#pragma unroll
            for (int j = 0; j < 3; ++j) {
                float val = lv * gai * gbv[j] + mv * ga[j] * gbi;
                val = (ii == j) ? val + mv * gg : val;
                atomicAdd(&row[c0 + j], val);
            }
        }
    }
    if (vsum != 0.f) atomicAdd(volslot, vsum);
    __syncthreads();

    size_t rowoff = (size_t)rowIdx * n3;
    int n34 = n3 >> 2;
    float4* K4 = (float4*)(Ks + rowoff);
    for (int k = threadIdx.x; k < n34; k += blockDim.x)
        K4[k] = ((float4*)row)[k];
    for (int k = (n34 << 2) + threadIdx.x; k < n3; k += blockDim.x)
        Ks[rowoff + k] = row[k];
    if (threadIdx.x == 0)
        Ms[(size_t)rowIdx * n3 + rowIdx] = rho * 0.25f * (*volslot);
}

// --------------------------- fallback scatter path ---------------------------
__global__ void __launch_bounds__(256)
fluid_assemble(const float* __restrict__ nodes, const int* __restrict__ elems,
               float* __restrict__ Kf, float* __restrict__ Mf, int nelem, int n)
{
    int e = blockIdx.x * blockDim.x + threadIdx.x;
    if (e >= nelem) return;
    const int4 nd = *reinterpret_cast<const int4*>(elems + 4ll * e);
    int ni[4] = { nd.x, nd.y, nd.z, nd.w };
    double g[4][3], vol;
    tet_grads(nodes, ni, g, vol);
#pragma unroll
    for (int a = 0; a < 4; ++a) {
        long long rowoff = (long long)ni[a] * n;
#pragma unroll
        for (int b = 0; b < 4; ++b) {
            double kv = vol * (g[a][0]*g[b][0] + g[a][1]*g[b][1] + g[a][2]*g[b][2]);
            double mv = vol * (a == b ? 0.3 : 0.1);
            atomicAdd(Kf + rowoff + ni[b], (float)kv);
            atomicAdd(Mf + rowoff + ni[b], (float)mv);
        }
    }
}

__global__ void __launch_bounds__(256)
solid_assemble(const float* __restrict__ nodes, const int* __restrict__ elems,
               float* __restrict__ Ks, float* __restrict__ Ms,
               const float* __restrict__ E_p, const float* __restrict__ nu_p,
               const float* __restrict__ rho_p, int nelem, int n3)
{
    int e = blockIdx.x * blockDim.x + threadIdx.x;
    if (e >= nelem) return;
    double E = (double)*E_p, nu = (double)*nu_p, rho = (double)*rho_p;
    double coeff = E / ((1.0 + nu) * (1.0 - 2.0 * nu));
    double lam = coeff * nu, mu = coeff * (1.0 - 2.0 * nu) * 0.5;
    const int4 nd = *reinterpret_cast<const int4*>(elems + 4ll * e);
    int ni[4] = { nd.x, nd.y, nd.z, nd.w };
    double g[4][3], vol;
    tet_grads(nodes, ni, g, vol);
    double lv = lam * vol, mv = mu * vol;
#pragma unroll
    for (int a = 0; a < 4; ++a) {
        long long row0 = 3ll * ni[a];
#pragma unroll
        for (int b = 0; b < 4; ++b) {
            long long col0 = 3ll * ni[b];
            double gg = g[a][0]*g[b][0] + g[a][1]*g[b][1] + g[a][2]*g[b][2];
#pragma unroll
            for (int i = 0; i < 3; ++i) {
                float* rowp = Ks + (row0 + i) * (long long)n3 + col0;
#pragma unroll
                for (int j = 0; j < 3; ++j) {
                    double val = lv * g[a][i] * g[b][j] + mv * g[a][j] * g[b][i];
                    if (i == j) val += mv * gg;
                    atomicAdd(rowp + j, (float)val);
                }
            }
        }
        float mval = (float)(rho * vol * 0.25);
#pragma unroll
        for (int i = 0; i < 3; ++i) {
            long long d = row0 + i;
            atomicAdd(Ms + d * (long long)n3 + d, mval);
        }
    }
}

// ---------------------------------------------------------------------------
extern "C" void kernel_launch(void* const* d_in, const int* in_sizes, int n_in,
                              void* d_out, int out_size, void* d_ws, size_t ws_size,
                              hipStream_t stream)
{
    const float* nodes = (const float*)d_in[0];
    const int*   fe    = (const int*)d_in[1];
    const int*   se    = (const int*)d_in[2];
    const float* E_p   = (const float*)d_in[3];
    const float* nu_p  = (const float*)d_in[4];
    const float* rho_p = (const float*)d_in[5];

    const int n  = in_sizes[0] / 3;
    const int nf = in_sizes[1] / 4;
    const int ns = in_sizes[2] / 4;
    const int n3 = 3 * n;

    float* out = (float*)d_out;
    float* Kf = out;
    float* Mf = Kf + (size_t)n * n;
    float* Ks = Mf + (size_t)n * n;
    float* Ms = Ks + (size_t)n3 * n3;

    // workspace layout
    size_t pos = 0;
    auto take = [&](size_t bytes) {
        size_t p = pos;
        pos = (pos + bytes + 255) & ~(size_t)255;
        return p;
    };
    size_t recF_o = take((size_t)nf * 64);
    size_t recS_o = take((size_t)ns * 64);
    size_t entF_o = take((size_t)4 * nf * 4);
    size_t entS_o = take((size_t)4 * ns * 4);
    size_t HF_o   = take((size_t)G_PART * n * 4);
    size_t HS_o   = take((size_t)G_PART * n * 4);
    size_t ints_o = take((size_t)(4 * n + 2) * 4);
    bool gather_ok = (pos <= ws_size);

    const int bs = 256;

    if (!gather_ok) {
        hipMemsetAsync(d_out, 0, (size_t)out_size * sizeof(float), stream);
        fluid_assemble<<<(nf + bs - 1) / bs, bs, 0, stream>>>(nodes, fe, Kf, Mf, nf, n);
        solid_assemble<<<(ns + bs - 1) / bs, bs, 0, stream>>>(nodes, se, Ks, Ms,
                                                              E_p, nu_p, rho_p, ns, n3);
        return;
    }

    char* ws = (char*)d_ws;
    float4* recF = (float4*)(ws + recF_o);
    float4* recS = (float4*)(ws + recS_o);
    int* entF = (int*)(ws + entF_o);
    int* entS = (int*)(ws + entS_o);
    int* HF   = (int*)(ws + HF_o);
    int* HS   = (int*)(ws + HS_o);
    int* ib   = (int*)(ws + ints_o);
    int* cntF = ib;
    int* cntS = ib + n;
    int* offF = ib + 2 * n;
    int* offS = ib + 3 * n + 1;

    const int4* fe4 = (const int4*)fe;
    const int4* se4 = (const int4*)se;

    // zero M_s (diagonal written by solid_gather; rest must be 0)
    hipMemsetAsync(Ms, 0, (size_t)n3 * n3 * sizeof(float), stream);

    // per-element records
    geom_rec<<<(nf + bs - 1) / bs, bs, 0, stream>>>(nodes, fe4, recF, nf);
    geom_rec<<<(ns + bs - 1) / bs, bs, 0, stream>>>(nodes, se4, recS, ns);

    // counting-sort inverted index
    int chunkF = (nf + G_PART - 1) / G_PART;
    int chunkS = (ns + G_PART - 1) / G_PART;
    size_t histLds = (size_t)n * sizeof(int);
    hist_part<<<G_PART, bs, histLds, stream>>>(fe4, HF, nf, n, chunkF);
    hist_part<<<G_PART, bs, histLds, stream>>>(se4, HS, ns, n, chunkS);
    int csBlocks = (n + bs - 1) / bs;
    colscan<<<csBlocks, bs, 0, stream>>>(HF, cntF, n);
    colscan<<<csBlocks, bs, 0, stream>>>(HS, cntS, n);
    scan_two<<<2, bs, 0, stream>>>(cntF, cntS, offF, offS, n);
    scatter_part<<<G_PART, bs, histLds, stream>>>(fe4, HF, offF, entF, nf, n, chunkF);
    scatter_part<<<G_PART, bs, histLds, stream>>>(se4, HS, offS, entS, ns, n, chunkS);

    // gather-assemble rows
    fluid_gather<<<n, bs, (size_t)2 * n * sizeof(float), stream>>>(
        entF, offF, recF, Kf, Mf, n);
    solid_gather<<<n3, bs, (size_t)(n3 + 1) * sizeof(float), stream>>>(
        entS, offS, recS, Ks, Ms, E_p, nu_p, rho_p, n, n3);
}

// Round 4
// 501.521 us; speedup vs baseline: 7.7436x; 1.1551x over previous
//
#include <hip/hip_runtime.h>

// ---------------------------------------------------------------------------
// CoupledFEMSolver — gather assembly, counting-sort index, diag-in-register.
//
// K_f, M_f (n x n) from fluid tets; K_s, M_s (3n x 3n) from solid tets.
//
// Geometry per tet (double precision; K entries ~ 1/det reach ~1e14):
//   det = r1.(r2 x r3); g1=(r2xr3)/det, g2=(r3xr1)/det, g3=(r1xr2)/det,
//   g0=-(g1+g2+g3); vol=|det|/6
// Fluid:  K_e[a][b] = vol*(ga.gb); M_e[a][b] = vol*(a==b ? .3 : .1)
// Solid:  K block (a,b) entry (i,j) =
//   vol*(lam*ga_i*gb_j + mu*ga_j*gb_i + (i==j)*mu*(ga.gb));
//   M_s diagonal only: rho*vol/4 per dof.
//
// Round-4 key change: every visit in row r has one b with cols[b]==r, so the
// old code hammered the SAME LDS addresses with 64-lane atomics every
// iteration (serialized RMW, invisible to the bank-conflict counter). The
// diagonal block is now accumulated in registers + wave shuffle-reduce; the
// three dof-rows of a solid node are assembled by ONE block (73.7 KB LDS).
// ---------------------------------------------------------------------------

#define G_PART 256

__device__ __forceinline__ void tet_grads(const float* __restrict__ nodes,
                                          const int* ni,
                                          double g[4][3], double& vol)
{
    double p[4][3];
#pragma unroll
    for (int a = 0; a < 4; ++a) {
        const float* q = nodes + 3ll * ni[a];
        p[a][0] = (double)q[0];
        p[a][1] = (double)q[1];
        p[a][2] = (double)q[2];
    }
    double r1[3], r2[3], r3[3];
#pragma unroll
    for (int k = 0; k < 3; ++k) {
        r1[k] = p[1][k] - p[0][k];
        r2[k] = p[2][k] - p[0][k];
        r3[k] = p[3][k] - p[0][k];
    }
    double c23[3] = { r2[1]*r3[2] - r2[2]*r3[1],
                      r2[2]*r3[0] - r2[0]*r3[2],
                      r2[0]*r3[1] - r2[1]*r3[0] };
    double det = r1[0]*c23[0] + r1[1]*c23[1] + r1[2]*c23[2];
    double inv = 1.0 / det;
    double c31[3] = { r3[1]*r1[2] - r3[2]*r1[1],
                      r3[2]*r1[0] - r3[0]*r1[2],
                      r3[0]*r1[1] - r3[1]*r1[0] };
    double c12[3] = { r1[1]*r2[2] - r1[2]*r2[1],
                      r1[2]*r2[0] - r1[0]*r2[2],
                      r1[0]*r2[1] - r1[1]*r2[0] };
#pragma unroll
    for (int k = 0; k < 3; ++k) {
        g[1][k] = c23[k] * inv;
        g[2][k] = c31[k] * inv;
        g[3][k] = c12[k] * inv;
        g[0][k] = -(g[1][k] + g[2][k] + g[3][k]);
    }
    vol = fabs(det) / 6.0;
}

__device__ __forceinline__ float sel4(float x0, float x1, float x2, float x3, int a) {
    float r = x0;
    r = (a == 1) ? x1 : r;
    r = (a == 2) ? x2 : r;
    r = (a == 3) ? x3 : r;
    return r;
}

__device__ __forceinline__ float wave_reduce(float v) {
#pragma unroll
    for (int m = 1; m < 64; m <<= 1) v += __shfl_xor(v, m, 64);
    return v;
}

// ------------------------- element records (64 B) ---------------------------
// q0=(g1x,g1y,g1z,g2x) q1=(g2y,g2z,g3x,g3y) q2=(g3z,vol,ndx,ndy) q3=(ndz,ndw,-,-)
__global__ void __launch_bounds__(256)
geom_rec(const float* __restrict__ nodes, const int4* __restrict__ elems,
         float4* __restrict__ rec, int nelem)
{
    int e = blockIdx.x * blockDim.x + threadIdx.x;
    if (e >= nelem) return;
    int4 nd = elems[e];
    int ni[4] = { nd.x, nd.y, nd.z, nd.w };
    double g[4][3], vol;
    tet_grads(nodes, ni, g, vol);
    rec[e*4+0] = make_float4((float)g[1][0], (float)g[1][1], (float)g[1][2], (float)g[2][0]);
    rec[e*4+1] = make_float4((float)g[2][1], (float)g[2][2], (float)g[3][0], (float)g[3][1]);
    rec[e*4+2] = make_float4((float)g[3][2], (float)vol,
                             __int_as_float(nd.x), __int_as_float(nd.y));
    rec[e*4+3] = make_float4(__int_as_float(nd.z), __int_as_float(nd.w), 0.f, 0.f);
}

#define UNPACK_REC(rec_, e_)                                                  \
    float4 q0 = (rec_)[(e_)*4+0], q1 = (rec_)[(e_)*4+1],                      \
           q2 = (rec_)[(e_)*4+2], q3 = (rec_)[(e_)*4+3];                      \
    const float gx[4] = { -(q0.x+q0.w+q1.z), q0.x, q0.w, q1.z };              \
    const float gy[4] = { -(q0.y+q1.x+q1.w), q0.y, q1.x, q1.w };              \
    const float gz[4] = { -(q0.z+q1.y+q2.x), q0.z, q1.y, q2.x };              \
    float vol = q2.y;                                                         \
    const int cols[4] = { __float_as_int(q2.z), __float_as_int(q2.w),         \
                          __float_as_int(q3.x), __float_as_int(q3.y) };

// --------------------- counting-sort inverted index -------------------------
__global__ void __launch_bounds__(256)
hist_part(const int4* __restrict__ elems, int* __restrict__ H,
          int nelem, int n, int chunk)
{
    extern __shared__ int h[];
    for (int i = threadIdx.x; i < n; i += blockDim.x) h[i] = 0;
    __syncthreads();
    int b = blockIdx.x;
    int beg = b * chunk, end = min(nelem, beg + chunk);
    for (int e = beg + threadIdx.x; e < end; e += blockDim.x) {
        int4 nd = elems[e];
        atomicAdd(&h[nd.x], 1);
        atomicAdd(&h[nd.y], 1);
        atomicAdd(&h[nd.z], 1);
        atomicAdd(&h[nd.w], 1);
    }
    __syncthreads();
    int* Hb = H + (size_t)b * n;
    for (int i = threadIdx.x; i < n; i += blockDim.x) Hb[i] = h[i];
}

__global__ void __launch_bounds__(256)
colscan(int* __restrict__ H, int* __restrict__ cnt, int n)
{
    int node = blockIdx.x * blockDim.x + threadIdx.x;
    if (node >= n) return;
    int s = 0;
    for (int b = 0; b < G_PART; ++b) {
        size_t idx = (size_t)b * n + node;
        int v = H[idx];
        H[idx] = s;
        s += v;
    }
    cnt[node] = s;
}

__global__ void __launch_bounds__(256)
scan_two(const int* __restrict__ cntF, const int* __restrict__ cntS,
         int* __restrict__ offF, int* __restrict__ offS, int n)
{
    const int* cnt = blockIdx.x ? cntS : cntF;
    int* off = blockIdx.x ? offS : offF;
    __shared__ int partial[256];
    int t = threadIdx.x;
    int ch = (n + 255) / 256;
    int base = t * ch;
    int s = 0;
    for (int k = 0; k < ch; ++k) {
        int i = base + k;
        if (i < n) s += cnt[i];
    }
    partial[t] = s;
    __syncthreads();
    for (int d = 1; d < 256; d <<= 1) {
        int v = (t >= d) ? partial[t - d] : 0;
        __syncthreads();
        partial[t] += v;
        __syncthreads();
    }
    int run = (t == 0) ? 0 : partial[t - 1];
    for (int k = 0; k < ch; ++k) {
        int i = base + k;
        if (i < n) { off[i] = run; run += cnt[i]; }
    }
    if (t == 255) off[n] = partial[255];
}

__global__ void __launch_bounds__(256)
scatter_part(const int4* __restrict__ elems, const int* __restrict__ H,
             const int* __restrict__ off, int* __restrict__ entries,
             int nelem, int n, int chunk)
{
    extern __shared__ int slot[];
    int b = blockIdx.x;
    const int* Hb = H + (size_t)b * n;
    for (int i = threadIdx.x; i < n; i += blockDim.x)
        slot[i] = off[i] + Hb[i];
    __syncthreads();
    int beg = b * chunk, end = min(nelem, beg + chunk);
    for (int e = beg + threadIdx.x; e < end; e += blockDim.x) {
        int4 nd = elems[e];
        int p;
        p = atomicAdd(&slot[nd.x], 1); entries[p] = e * 4 + 0;
        p = atomicAdd(&slot[nd.y], 1); entries[p] = e * 4 + 1;
        p = atomicAdd(&slot[nd.z], 1); entries[p] = e * 4 + 2;
        p = atomicAdd(&slot[nd.w], 1); entries[p] = e * 4 + 3;
    }
}

// ------------------------------- fluid gather -------------------------------
// one block per node r; K row + M row in LDS; diagonal (col==r) in registers.
__global__ void __launch_bounds__(512)
fluid_gather(const int* __restrict__ entries, const int* __restrict__ off,
             const float4* __restrict__ rec,
             float* __restrict__ Kf, float* __restrict__ Mf, int n)
{
    extern __shared__ unsigned char smem[];
    float* Krow = (float*)smem;          // n
    float* Mrow = Krow + n;              // n
    float* acc  = Mrow + n;              // [0]=Kdiag [1]=Mdiag
    int tid = threadIdx.x;

    {
        float4* v = (float4*)Krow;
        int cnt = (2 * n) >> 2;
        for (int i = tid; i < cnt; i += blockDim.x) v[i] = make_float4(0.f,0.f,0.f,0.f);
        if (tid < 2) acc[tid] = 0.f;
    }
    __syncthreads();

    int r = blockIdx.x;
    int beg = off[r], end = off[r + 1];
    float dK = 0.f, dM = 0.f;
    for (int idx = beg + tid; idx < end; idx += blockDim.x) {
        int packed = entries[idx];
        int e = packed >> 2, a = packed & 3;
        UNPACK_REC(rec, e);
        float gax = sel4(gx[0], gx[1], gx[2], gx[3], a);
        float gay = sel4(gy[0], gy[1], gy[2], gy[3], a);
        float gaz = sel4(gz[0], gz[1], gz[2], gz[3], a);
#pragma unroll
        for (int b = 0; b < 4; ++b) {
            float kv = vol * (gax*gx[b] + gay*gy[b] + gaz*gz[b]);
            int c = cols[b];
            if (c == r) {                  // b == a (node ids distinct)
                dK += kv;
                dM += vol * 0.3f;
            } else {
                atomicAdd(&Krow[c], kv);
                atomicAdd(&Mrow[c], vol * 0.1f);
            }
        }
    }
    dK = wave_reduce(dK);
    dM = wave_reduce(dM);
    if ((tid & 63) == 0) {
        if (dK != 0.f) atomicAdd(&acc[0], dK);
        if (dM != 0.f) atomicAdd(&acc[1], dM);
    }
    __syncthreads();
    if (tid == 0) { Krow[r] += acc[0]; Mrow[r] += acc[1]; }
    __syncthreads();

    size_t rowoff = (size_t)r * n;
    int n4 = n >> 2;
    float4* K4 = (float4*)(Kf + rowoff);
    float4* M4 = (float4*)(Mf + rowoff);
    for (int i = tid; i < n4; i += blockDim.x) {
        K4[i] = ((float4*)Krow)[i];
        M4[i] = ((float4*)Mrow)[i];
    }
}

// ------------------------------- solid gather -------------------------------
// one block per node r: ALL THREE dof rows (3 x 3n) in LDS; diagonal 3x3
// block (col node == r) accumulated in registers + wave reduce.
__global__ void __launch_bounds__(512)
solid_gather(const int* __restrict__ entries, const int* __restrict__ off,
             const float4* __restrict__ rec,
             float* __restrict__ Ks, float* __restrict__ Ms,
             const float* __restrict__ E_p, const float* __restrict__ nu_p,
             const float* __restrict__ rho_p, int n, int n3)
{
    extern __shared__ unsigned char smem[];
    float* row  = (float*)smem;          // 3*n3: row[i*n3 + c]
    float* dacc = row + 3 * n3;          // 9 diag slots
    float* vacc = dacc + 9;              // vol sum
    int tid = threadIdx.x;

    {
        float4* v = (float4*)row;
        int cnt = (3 * n3) >> 2;
        for (int k = tid; k < cnt; k += blockDim.x) v[k] = make_float4(0.f,0.f,0.f,0.f);
        if (tid < 10) dacc[tid] = 0.f;   // covers vacc as dacc[9]
    }
    __syncthreads();

    int r = blockIdx.x;
    float E = *E_p, nu = *nu_p, rho = *rho_p;
    float coeff = E / ((1.f + nu) * (1.f - 2.f * nu));
    float lam = coeff * nu;
    float mu  = coeff * (1.f - 2.f * nu) * 0.5f;

    float d00=0.f,d01=0.f,d02=0.f,d10=0.f,d11=0.f,d12=0.f,d20=0.f,d21=0.f,d22=0.f;
    float vsum = 0.f;

    int beg = off[r], end = off[r + 1];
    for (int idx = beg + tid; idx < end; idx += blockDim.x) {
        int packed = entries[idx];
        int e = packed >> 2, a = packed & 3;
        UNPACK_REC(rec, e);
        vsum += vol;
        float gax = sel4(gx[0], gx[1], gx[2], gx[3], a);
        float gay = sel4(gy[0], gy[1], gy[2], gy[3], a);
        float gaz = sel4(gz[0], gz[1], gz[2], gz[3], a);
        float lv = lam * vol, mv = mu * vol;
        float la0 = lv*gax, la1 = lv*gay, la2 = lv*gaz;
        float ma0 = mv*gax, ma1 = mv*gay, ma2 = mv*gaz;
#pragma unroll
        for (int b = 0; b < 4; ++b) {
            float gb0 = gx[b], gb1 = gy[b], gb2 = gz[b];
            float mgg = mv * (gax*gb0 + gay*gb1 + gaz*gb2);
            // val(i,j) = lv*ga_i*gb_j + mv*ga_j*gb_i + (i==j)*mgg
            float v00 = la0*gb0 + ma0*gb0 + mgg;
            float v01 = la0*gb1 + ma1*gb0;
            float v02 = la0*gb2 + ma2*gb0;
            float v10 = la1*gb0 + ma0*gb1;
            float v11 = la1*gb1 + ma1*gb1 + mgg;
            float v12 = la1*gb2 + ma2*gb1;
            float v20 = la2*gb0 + ma0*gb2;
            float v21 = la2*gb1 + ma1*gb2;
            float v22 = la2*gb2 + ma2*gb2 + mgg;
            int c = cols[b];
            if (c == r) {                // b == a
                d00+=v00; d01+=v01; d02+=v02;
                d10+=v10; d11+=v11; d12+=v12;
                d20+=v20; d21+=v21; d22+=v22;
            } else {
                int c0 = 3 * c;
                atomicAdd(&row[c0+0],        v00);
                atomicAdd(&row[c0+1],        v01);
                atomicAdd(&row[c0+2],        v02);
                atomicAdd(&row[n3+c0+0],     v10);
                atomicAdd(&row[n3+c0+1],     v11);
                atomicAdd(&row[n3+c0+2],     v12);
                atomicAdd(&row[2*n3+c0+0],   v20);
                atomicAdd(&row[2*n3+c0+1],   v21);
                atomicAdd(&row[2*n3+c0+2],   v22);
            }
        }
    }
    d00 = wave_reduce(d00); d01 = wave_reduce(d01); d02 = wave_reduce(d02);
    d10 = wave_reduce(d10); d11 = wave_reduce(d11); d12 = wave_reduce(d12);
    d20 = wave_reduce(d20); d21 = wave_reduce(d21); d22 = wave_reduce(d22);
    vsum = wave_reduce(vsum);
    if ((tid & 63) == 0) {
        atomicAdd(&dacc[0], d00); atomicAdd(&dacc[1], d01); atomicAdd(&dacc[2], d02);
        atomicAdd(&dacc[3], d10); atomicAdd(&dacc[4], d11); atomicAdd(&dacc[5], d12);
        atomicAdd(&dacc[6], d20); atomicAdd(&dacc[7], d21); atomicAdd(&dacc[8], d22);
        atomicAdd(vacc, vsum);
    }
    __syncthreads();
    if (tid < 9) {
        int i = tid / 3, j = tid - 3 * i;
        row[i * n3 + 3 * r + j] += dacc[tid];
    }
    __syncthreads();

    // rows 3r, 3r+1, 3r+2 are contiguous in Ks — one 3*n3 coalesced store
    {
        float4* dst = (float4*)(Ks + (size_t)3 * r * n3);
        float4* src = (float4*)row;
        int cnt = (3 * n3) >> 2;
        for (int k = tid; k < cnt; k += blockDim.x) dst[k] = src[k];
    }
    if (tid < 3) {
        size_t d = (size_t)(3 * r + tid);
        Ms[d * n3 + d] = rho * 0.25f * (*vacc);
    }
}

// --------------------------- fallback scatter path ---------------------------
__global__ void __launch_bounds__(256)
fluid_assemble(const float* __restrict__ nodes, const int* __restrict__ elems,
               float* __restrict__ Kf, float* __restrict__ Mf, int nelem, int n)
{
    int e = blockIdx.x * blockDim.x + threadIdx.x;
    if (e >= nelem) return;
    const int4 nd = *reinterpret_cast<const int4*>(elems + 4ll * e);
    int ni[4] = { nd.x, nd.y, nd.z, nd.w };
    double g[4][3], vol;
    tet_grads(nodes, ni, g, vol);
#pragma unroll
    for (int a = 0; a < 4; ++a) {
        long long rowoff = (long long)ni[a] * n;
#pragma unroll
        for (int b = 0; b < 4; ++b) {
            double kv = vol * (g[a][0]*g[b][0] + g[a][1]*g[b][1] + g[a][2]*g[b][2]);
            double mv = vol * (a == b ? 0.3 : 0.1);
            atomicAdd(Kf + rowoff + ni[b], (float)kv);
            atomicAdd(Mf + rowoff + ni[b], (float)mv);
        }
    }
}

__global__ void __launch_bounds__(256)
solid_assemble(const float* __restrict__ nodes, const int* __restrict__ elems,
               float* __restrict__ Ks, float* __restrict__ Ms,
               const float* __restrict__ E_p, const float* __restrict__ nu_p,
               const float* __restrict__ rho_p, int nelem, int n3)
{
    int e = blockIdx.x * blockDim.x + threadIdx.x;
    if (e >= nelem) return;
    double E = (double)*E_p, nu = (double)*nu_p, rho = (double)*rho_p;
    double coeff = E / ((1.0 + nu) * (1.0 - 2.0 * nu));
    double lam = coeff * nu, mu = coeff * (1.0 - 2.0 * nu) * 0.5;
    const int4 nd = *reinterpret_cast<const int4*>(elems + 4ll * e);
    int ni[4] = { nd.x, nd.y, nd.z, nd.w };
    double g[4][3], vol;
    tet_grads(nodes, ni, g, vol);
    double lv = lam * vol, mv = mu * vol;
#pragma unroll
    for (int a = 0; a < 4; ++a) {
        long long row0 = 3ll * ni[a];
#pragma unroll
        for (int b = 0; b < 4; ++b) {
            long long col0 = 3ll * ni[b];
            double gg = g[a][0]*g[b][0] + g[a][1]*g[b][1] + g[a][2]*g[b][2];
#pragma unroll
            for (int i = 0; i < 3; ++i) {
                float* rowp = Ks + (row0 + i) * (long long)n3 + col0;
#pragma unroll
                for (int j = 0; j < 3; ++j) {
                    double val = lv * g[a][i] * g[b][j] + mv * g[a][j] * g[b][i];
                    if (i == j) val += mv * gg;
                    atomicAdd(rowp + j, (float)val);
                }
            }
        }
        float mval = (float)(rho * vol * 0.25);
#pragma unroll
        for (int i = 0; i < 3; ++i) {
            long long d = row0 + i;
            atomicAdd(Ms + d * (long long)n3 + d, mval);
        }
    }
}

// ---------------------------------------------------------------------------
extern "C" void kernel_launch(void* const* d_in, const int* in_sizes, int n_in,
                              void* d_out, int out_size, void* d_ws, size_t ws_size,
                              hipStream_t stream)
{
    const float* nodes = (const float*)d_in[0];
    const int*   fe    = (const int*)d_in[1];
    const int*   se    = (const int*)d_in[2];
    const float* E_p   = (const float*)d_in[3];
    const float* nu_p  = (const float*)d_in[4];
    const float* rho_p = (const float*)d_in[5];

    const int n  = in_sizes[0] / 3;
    const int nf = in_sizes[1] / 4;
    const int ns = in_sizes[2] / 4;
    const int n3 = 3 * n;

    float* out = (float*)d_out;
    float* Kf = out;
    float* Mf = Kf + (size_t)n * n;
    float* Ks = Mf + (size_t)n * n;
    float* Ms = Ks + (size_t)n3 * n3;

    size_t pos = 0;
    auto take = [&](size_t bytes) {
        size_t p = pos;
        pos = (pos + bytes + 255) & ~(size_t)255;
        return p;
    };
    size_t recF_o = take((size_t)nf * 64);
    size_t recS_o = take((size_t)ns * 64);
    size_t entF_o = take((size_t)4 * nf * 4);
    size_t entS_o = take((size_t)4 * ns * 4);
    size_t HF_o   = take((size_t)G_PART * n * 4);
    size_t HS_o   = take((size_t)G_PART * n * 4);
    size_t ints_o = take((size_t)(4 * n + 2) * 4);
    bool gather_ok = (pos <= ws_size);

    const int bs = 256;

    if (!gather_ok) {
        hipMemsetAsync(d_out, 0, (size_t)out_size * sizeof(float), stream);
        fluid_assemble<<<(nf + bs - 1) / bs, bs, 0, stream>>>(nodes, fe, Kf, Mf, nf, n);
        solid_assemble<<<(ns + bs - 1) / bs, bs, 0, stream>>>(nodes, se, Ks, Ms,
                                                              E_p, nu_p, rho_p, ns, n3);
        return;
    }

    char* ws = (char*)d_ws;
    float4* recF = (float4*)(ws + recF_o);
    float4* recS = (float4*)(ws + recS_o);
    int* entF = (int*)(ws + entF_o);
    int* entS = (int*)(ws + entS_o);
    int* HF   = (int*)(ws + HF_o);
    int* HS   = (int*)(ws + HS_o);
    int* ib   = (int*)(ws + ints_o);
    int* cntF = ib;
    int* cntS = ib + n;
    int* offF = ib + 2 * n;
    int* offS = ib + 3 * n + 1;

    const int4* fe4 = (const int4*)fe;
    const int4* se4 = (const int4*)se;

    // zero M_s (diagonal written by solid_gather; rest must be 0)
    hipMemsetAsync(Ms, 0, (size_t)n3 * n3 * sizeof(float), stream);

    geom_rec<<<(nf + bs - 1) / bs, bs, 0, stream>>>(nodes, fe4, recF, nf);
    geom_rec<<<(ns + bs - 1) / bs, bs, 0, stream>>>(nodes, se4, recS, ns);

    int chunkF = (nf + G_PART - 1) / G_PART;
    int chunkS = (ns + G_PART - 1) / G_PART;
    size_t histLds = (size_t)n * sizeof(int);
    hist_part<<<G_PART, bs, histLds, stream>>>(fe4, HF, nf, n, chunkF);
    hist_part<<<G_PART, bs, histLds, stream>>>(se4, HS, ns, n, chunkS);
    int csBlocks = (n + bs - 1) / bs;
    colscan<<<csBlocks, bs, 0, stream>>>(HF, cntF, n);
    colscan<<<csBlocks, bs, 0, stream>>>(HS, cntS, n);
    scan_two<<<2, bs, 0, stream>>>(cntF, cntS, offF, offS, n);
    scatter_part<<<G_PART, bs, histLds, stream>>>(fe4, HF, offF, entF, nf, n, chunkF);
    scatter_part<<<G_PART, bs, histLds, stream>>>(se4, HS, offS, entS, ns, n, chunkS);

    // gather-assemble
    fluid_gather<<<n, 512, (size_t)(2 * n + 2) * sizeof(float), stream>>>(
        entF, offF, recF, Kf, Mf, n);
    solid_gather<<<n, 512, (size_t)(3 * n3 + 10) * sizeof(float), stream>>>(
        entS, offS, recS, Ks, Ms, E_p, nu_p, rho_p, n, n3);
}

// Round 5
// 346.114 us; speedup vs baseline: 11.2205x; 1.4490x over previous
//
#include <hip/hip_runtime.h>

// ---------------------------------------------------------------------------
// CoupledFEMSolver — gather assembly; LDS accumulation via claim-arbitrated
// PLAIN writes (no LDS atomic RMW in the gather kernels).
//
// Why: measured LDS f32 atomicAdd throughput is ~0.29 lane-ops/cycle/CU
// (r3: 57.6M atomics/323us, r4: 43.2M/268us — constant, occupancy-independent).
// Plain ds_read/ds_write run ~25x faster per wave-op. The claim loop gives
// each column exactly one exclusive writer per round:
//   round: pending threads write claim[col]=tid; __syncthreads();
//          the surviving writer (winner) read-add-writes its values (plain),
//          advances to its next pair; losers retry. ~10-14 rounds/block.
//
// Geometry per tet (double precision; K entries ~ 1/det reach ~1e14):
//   det = r1.(r2 x r3); g1=(r2xr3)/det, g2=(r3xr1)/det, g3=(r1xr2)/det,
//   g0=-(g1+g2+g3); vol=|det|/6
// Fluid:  K_e[a][b] = vol*(ga.gb); M_e[a][b] = vol*(a==b ? .3 : .1)
// Solid:  K block (a,b) entry (i,j) =
//   vol*(lam*ga_i*gb_j + mu*ga_j*gb_i + (i==j)*mu*(ga.gb));
//   M_s diagonal only: rho*vol/4 per dof.
// Diagonal (b==a) contributions accumulate in registers + wave reduce.
// ---------------------------------------------------------------------------

#define G_PART 256

__device__ __forceinline__ void tet_grads(const float* __restrict__ nodes,
                                          const int* ni,
                                          double g[4][3], double& vol)
{
    double p[4][3];
#pragma unroll
    for (int a = 0; a < 4; ++a) {
        const float* q = nodes + 3ll * ni[a];
        p[a][0] = (double)q[0];
        p[a][1] = (double)q[1];
        p[a][2] = (double)q[2];
    }
    double r1[3], r2[3], r3[3];
#pragma unroll
    for (int k = 0; k < 3; ++k) {
        r1[k] = p[1][k] - p[0][k];
        r2[k] = p[2][k] - p[0][k];
        r3[k] = p[3][k] - p[0][k];
    }
    double c23[3] = { r2[1]*r3[2] - r2[2]*r3[1],
                      r2[2]*r3[0] - r2[0]*r3[2],
                      r2[0]*r3[1] - r2[1]*r3[0] };
    double det = r1[0]*c23[0] + r1[1]*c23[1] + r1[2]*c23[2];
    double inv = 1.0 / det;
    double c31[3] = { r3[1]*r1[2] - r3[2]*r1[1],
                      r3[2]*r1[0] - r3[0]*r1[2],
                      r3[0]*r1[1] - r3[1]*r1[0] };
    double c12[3] = { r1[1]*r2[2] - r1[2]*r2[1],
                      r1[2]*r2[0] - r1[0]*r2[2],
                      r1[0]*r2[1] - r1[1]*r2[0] };
#pragma unroll
    for (int k = 0; k < 3; ++k) {
        g[1][k] = c23[k] * inv;
        g[2][k] = c31[k] * inv;
        g[3][k] = c12[k] * inv;
        g[0][k] = -(g[1][k] + g[2][k] + g[3][k]);
    }
    vol = fabs(det) / 6.0;
}

__device__ __forceinline__ float sel4(float x0, float x1, float x2, float x3, int a) {
    float r = x0;
    r = (a == 1) ? x1 : r;
    r = (a == 2) ? x2 : r;
    r = (a == 3) ? x3 : r;
    return r;
}
__device__ __forceinline__ int sel4i(int x0, int x1, int x2, int x3, int a) {
    int r = x0;
    r = (a == 1) ? x1 : r;
    r = (a == 2) ? x2 : r;
    r = (a == 3) ? x3 : r;
    return r;
}

__device__ __forceinline__ float wave_reduce(float v) {
#pragma unroll
    for (int m = 1; m < 64; m <<= 1) v += __shfl_xor(v, m, 64);
    return v;
}

// ------------------------- element records (64 B) ---------------------------
// q0=(g1x,g1y,g1z,g2x) q1=(g2y,g2z,g3x,g3y) q2=(g3z,vol,ndx,ndy) q3=(ndz,ndw,-,-)
__global__ void __launch_bounds__(256)
geom_rec(const float* __restrict__ nodes, const int4* __restrict__ elems,
         float4* __restrict__ rec, int nelem)
{
    int e = blockIdx.x * blockDim.x + threadIdx.x;
    if (e >= nelem) return;
    int4 nd = elems[e];
    int ni[4] = { nd.x, nd.y, nd.z, nd.w };
    double g[4][3], vol;
    tet_grads(nodes, ni, g, vol);
    rec[e*4+0] = make_float4((float)g[1][0], (float)g[1][1], (float)g[1][2], (float)g[2][0]);
    rec[e*4+1] = make_float4((float)g[2][1], (float)g[2][2], (float)g[3][0], (float)g[3][1]);
    rec[e*4+2] = make_float4((float)g[3][2], (float)vol,
                             __int_as_float(nd.x), __int_as_float(nd.y));
    rec[e*4+3] = make_float4(__int_as_float(nd.z), __int_as_float(nd.w), 0.f, 0.f);
}

// --------------------- counting-sort inverted index -------------------------
__global__ void __launch_bounds__(256)
hist_part(const int4* __restrict__ elems, int* __restrict__ H,
          int nelem, int n, int chunk)
{
    extern __shared__ int h[];
    for (int i = threadIdx.x; i < n; i += blockDim.x) h[i] = 0;
    __syncthreads();
    int b = blockIdx.x;
    int beg = b * chunk, end = min(nelem, beg + chunk);
    for (int e = beg + threadIdx.x; e < end; e += blockDim.x) {
        int4 nd = elems[e];
        atomicAdd(&h[nd.x], 1);
        atomicAdd(&h[nd.y], 1);
        atomicAdd(&h[nd.z], 1);
        atomicAdd(&h[nd.w], 1);
    }
    __syncthreads();
    int* Hb = H + (size_t)b * n;
    for (int i = threadIdx.x; i < n; i += blockDim.x) Hb[i] = h[i];
}

__global__ void __launch_bounds__(256)
colscan(int* __restrict__ H, int* __restrict__ cnt, int n)
{
    int node = blockIdx.x * blockDim.x + threadIdx.x;
    if (node >= n) return;
    int s = 0;
    for (int b = 0; b < G_PART; ++b) {
        size_t idx = (size_t)b * n + node;
        int v = H[idx];
        H[idx] = s;
        s += v;
    }
    cnt[node] = s;
}

__global__ void __launch_bounds__(256)
scan_two(const int* __restrict__ cntF, const int* __restrict__ cntS,
         int* __restrict__ offF, int* __restrict__ offS, int n)
{
    const int* cnt = blockIdx.x ? cntS : cntF;
    int* off = blockIdx.x ? offS : offF;
    __shared__ int partial[256];
    int t = threadIdx.x;
    int ch = (n + 255) / 256;
    int base = t * ch;
    int s = 0;
    for (int k = 0; k < ch; ++k) {
        int i = base + k;
        if (i < n) s += cnt[i];
    }
    partial[t] = s;
    __syncthreads();
    for (int d = 1; d < 256; d <<= 1) {
        int v = (t >= d) ? partial[t - d] : 0;
        __syncthreads();
        partial[t] += v;
        __syncthreads();
    }
    int run = (t == 0) ? 0 : partial[t - 1];
    for (int k = 0; k < ch; ++k) {
        int i = base + k;
        if (i < n) { off[i] = run; run += cnt[i]; }
    }
    if (t == 255) off[n] = partial[255];
}

__global__ void __launch_bounds__(256)
scatter_part(const int4* __restrict__ elems, const int* __restrict__ H,
             const int* __restrict__ off, int* __restrict__ entries,
             int nelem, int n, int chunk)
{
    extern __shared__ int slot[];
    int b = blockIdx.x;
    const int* Hb = H + (size_t)b * n;
    for (int i = threadIdx.x; i < n; i += blockDim.x)
        slot[i] = off[i] + Hb[i];
    __syncthreads();
    int beg = b * chunk, end = min(nelem, beg + chunk);
    for (int e = beg + threadIdx.x; e < end; e += blockDim.x) {
        int4 nd = elems[e];
        int p;
        p = atomicAdd(&slot[nd.x], 1); entries[p] = e * 4 + 0;
        p = atomicAdd(&slot[nd.y], 1); entries[p] = e * 4 + 1;
        p = atomicAdd(&slot[nd.z], 1); entries[p] = e * 4 + 2;
        p = atomicAdd(&slot[nd.w], 1); entries[p] = e * 4 + 3;
    }
}

// ------------------------------- fluid gather -------------------------------
// block per node r. val[c][2] = {K,M}. Claim-arbitrated plain accumulation.
__global__ void __launch_bounds__(512)
fluid_gather(const int* __restrict__ entries, const int* __restrict__ off,
             const float4* __restrict__ rec,
             float* __restrict__ Kf, float* __restrict__ Mf, int n)
{
    extern __shared__ unsigned char smem[];
    float* val = (float*)smem;                              // n*2
    unsigned short* claim = (unsigned short*)(val + 2 * n); // n
    float* dred = (float*)(claim + n);                      // 8*2 + 2

    const int tid = threadIdx.x;
    const int r = blockIdx.x;

    {
        float4* v = (float4*)val;
        int cnt = (2 * n) >> 2;
        for (int k = tid; k < cnt; k += blockDim.x) v[k] = make_float4(0.f,0.f,0.f,0.f);
    }

    int beg = off[r], end = off[r + 1];
    int idx = beg + tid;
    bool haveE = false, pending = false;
    int a = 0, bslot = 0, col = 0;
    int c0=0,c1=0,c2=0,c3=0;
    float gx0=0,gx1=0,gx2=0,gx3=0, gy0=0,gy1=0,gy2=0,gy3=0, gz0=0,gz1=0,gz2=0,gz3=0;
    float volv=0, ga0=0, ga1=0, ga2=0;
    float vK=0, vM=0;
    float dK=0.f, dM=0.f;

    auto advance = [&]() {
        while (!pending) {
            if (!haveE) {
                if (idx >= end) return;
                int packed = entries[idx];
                int e = packed >> 2; a = packed & 3;
                float4 q0 = rec[e*4+0], q1 = rec[e*4+1], q2 = rec[e*4+2], q3 = rec[e*4+3];
                gx1=q0.x; gy1=q0.y; gz1=q0.z; gx2=q0.w; gy2=q1.x; gz2=q1.y;
                gx3=q1.z; gy3=q1.w; gz3=q2.x; volv=q2.y;
                gx0=-(gx1+gx2+gx3); gy0=-(gy1+gy2+gy3); gz0=-(gz1+gz2+gz3);
                c0=__float_as_int(q2.z); c1=__float_as_int(q2.w);
                c2=__float_as_int(q3.x); c3=__float_as_int(q3.y);
                ga0=sel4(gx0,gx1,gx2,gx3,a);
                ga1=sel4(gy0,gy1,gy2,gy3,a);
                ga2=sel4(gz0,gz1,gz2,gz3,a);
                dK += volv * (ga0*ga0 + ga1*ga1 + ga2*ga2);
                dM += volv * 0.3f;
                haveE = true; bslot = 0;
            }
            int b = bslot + ((bslot >= a) ? 1 : 0);
            float gb0=sel4(gx0,gx1,gx2,gx3,b);
            float gb1=sel4(gy0,gy1,gy2,gy3,b);
            float gb2=sel4(gz0,gz1,gz2,gz3,b);
            col = sel4i(c0,c1,c2,c3,b);
            vK = volv * (ga0*gb0 + ga1*gb1 + ga2*gb2);
            vM = volv * 0.1f;
            ++bslot;
            if (bslot == 3) { haveE = false; idx += blockDim.x; }
            pending = true;
        }
    };

    advance();
    __syncthreads();   // val init complete before any winner RMW

    int live = __syncthreads_count(pending ? 1 : 0);
    while (live) {
        if (pending) claim[col] = (unsigned short)tid;
        __syncthreads();
        if (pending && claim[col] == (unsigned short)tid) {
            float* p = val + 2 * col;
            p[0] += vK;
            p[1] += vM;
            pending = false;
            advance();
        }
        live = __syncthreads_count(pending ? 1 : 0);
    }

    // diagonal reduction (register -> per-wave slots -> sum)
    dK = wave_reduce(dK);
    dM = wave_reduce(dM);
    if ((tid & 63) == 0) { int w = tid >> 6; dred[w*2+0] = dK; dred[w*2+1] = dM; }
    __syncthreads();
    if (tid < 2) {
        float s = 0.f;
        for (int w = 0; w < 8; ++w) s += dred[w*2 + tid];
        dred[16 + tid] = s;
    }
    __syncthreads();
    if (tid == 0) { val[2*r] += dred[16]; val[2*r+1] += dred[17]; }
    __syncthreads();

    // coalesced row stores
    size_t rowoff = (size_t)r * n;
    int q = n >> 2;
    float4* K4 = (float4*)(Kf + rowoff);
    float4* M4 = (float4*)(Mf + rowoff);
    for (int c4 = tid; c4 < q; c4 += blockDim.x) {
        int c = c4 << 2;
        K4[c4] = make_float4(val[2*c], val[2*(c+1)], val[2*(c+2)], val[2*(c+3)]);
        M4[c4] = make_float4(val[2*c+1], val[2*(c+1)+1], val[2*(c+2)+1], val[2*(c+3)+1]);
    }
}

// ------------------------------- solid gather -------------------------------
// block per node r. val[c][9] (col-major 3x3 blocks). Claim-arbitrated plain
// accumulation; diagonal 3x3 block in registers + wave reduce.
__global__ void __launch_bounds__(512)
solid_gather(const int* __restrict__ entries, const int* __restrict__ off,
             const float4* __restrict__ rec,
             float* __restrict__ Ks, float* __restrict__ Ms,
             const float* __restrict__ E_p, const float* __restrict__ nu_p,
             const float* __restrict__ rho_p, int n, int n3)
{
    extern __shared__ unsigned char smem[];
    float* val = (float*)smem;                              // n*9
    unsigned short* claim = (unsigned short*)(val + 9 * n); // n
    float* dred = (float*)(claim + n);                      // 8*10 + 10

    const int tid = threadIdx.x;
    const int r = blockIdx.x;

    {
        float4* v = (float4*)val;
        int cnt = (9 * n) >> 2;   // 9*n divisible by 4 for n=2048
        for (int k = tid; k < cnt; k += blockDim.x) v[k] = make_float4(0.f,0.f,0.f,0.f);
        int rem = 9 * n - (cnt << 2);
        for (int k = (cnt << 2) + tid; k < 9 * n; k += blockDim.x) val[k] = 0.f;
        (void)rem;
    }

    float E = *E_p, nu = *nu_p, rho = *rho_p;
    float coeff = E / ((1.f + nu) * (1.f - 2.f * nu));
    float lam = coeff * nu;
    float mu  = coeff * (1.f - 2.f * nu) * 0.5f;

    int beg = off[r], end = off[r + 1];
    int idx = beg + tid;
    bool haveE = false, pending = false;
    int a = 0, bslot = 0, col = 0;
    int c0=0,c1=0,c2=0,c3=0;
    float gx0=0,gx1=0,gx2=0,gx3=0, gy0=0,gy1=0,gy2=0,gy3=0, gz0=0,gz1=0,gz2=0,gz3=0;
    float volv=0, ga0=0, ga1=0, ga2=0;
    float v00=0,v01=0,v02=0,v10=0,v11=0,v12=0,v20=0,v21=0,v22=0;
    float d00=0,d01=0,d02=0,d10=0,d11=0,d12=0,d20=0,d21=0,d22=0, vsum=0;

    auto advance = [&]() {
        while (!pending) {
            if (!haveE) {
                if (idx >= end) return;
                int packed = entries[idx];
                int e = packed >> 2; a = packed & 3;
                float4 q0 = rec[e*4+0], q1 = rec[e*4+1], q2 = rec[e*4+2], q3 = rec[e*4+3];
                gx1=q0.x; gy1=q0.y; gz1=q0.z; gx2=q0.w; gy2=q1.x; gz2=q1.y;
                gx3=q1.z; gy3=q1.w; gz3=q2.x; volv=q2.y;
                gx0=-(gx1+gx2+gx3); gy0=-(gy1+gy2+gy3); gz0=-(gz1+gz2+gz3);
                c0=__float_as_int(q2.z); c1=__float_as_int(q2.w);
                c2=__float_as_int(q3.x); c3=__float_as_int(q3.y);
                ga0=sel4(gx0,gx1,gx2,gx3,a);
                ga1=sel4(gy0,gy1,gy2,gy3,a);
                ga2=sel4(gz0,gz1,gz2,gz3,a);
                // diagonal block (b == a): v_ij = (lam+mu)*vol*ga_i*ga_j + d_ij*mu*vol*(ga.ga)
                {
                    float lv = lam * volv, mv = mu * volv;
                    float lm = lv + mv;
                    float mgg = mv * (ga0*ga0 + ga1*ga1 + ga2*ga2);
                    d00 += lm*ga0*ga0 + mgg; d01 += lm*ga0*ga1;       d02 += lm*ga0*ga2;
                    d10 += lm*ga1*ga0;       d11 += lm*ga1*ga1 + mgg; d12 += lm*ga1*ga2;
                    d20 += lm*ga2*ga0;       d21 += lm*ga2*ga1;       d22 += lm*ga2*ga2 + mgg;
                }
                vsum += volv;
                haveE = true; bslot = 0;
            }
            int b = bslot + ((bslot >= a) ? 1 : 0);
            float gb0=sel4(gx0,gx1,gx2,gx3,b);
            float gb1=sel4(gy0,gy1,gy2,gy3,b);
            float gb2=sel4(gz0,gz1,gz2,gz3,b);
            col = sel4i(c0,c1,c2,c3,b);
            float lv = lam * volv, mv = mu * volv;
            float la0=lv*ga0, la1=lv*ga1, la2=lv*ga2;
            float ma0=mv*ga0, ma1=mv*ga1, ma2=mv*ga2;
            float mgg = mv * (ga0*gb0 + ga1*gb1 + ga2*gb2);
            v00 = la0*gb0 + ma0*gb0 + mgg;
            v01 = la0*gb1 + ma1*gb0;
            v02 = la0*gb2 + ma2*gb0;
            v10 = la1*gb0 + ma0*gb1;
            v11 = la1*gb1 + ma1*gb1 + mgg;
            v12 = la1*gb2 + ma2*gb1;
            v20 = la2*gb0 + ma0*gb2;
            v21 = la2*gb1 + ma1*gb2;
            v22 = la2*gb2 + ma2*gb2 + mgg;
            ++bslot;
            if (bslot == 3) { haveE = false; idx += blockDim.x; }
            pending = true;
        }
    };

    advance();
    __syncthreads();   // val init complete before any winner RMW

    int live = __syncthreads_count(pending ? 1 : 0);
    while (live) {
        if (pending) claim[col] = (unsigned short)tid;
        __syncthreads();
        if (pending && claim[col] == (unsigned short)tid) {
            float* p = val + 9 * col;
            p[0]+=v00; p[1]+=v01; p[2]+=v02;
            p[3]+=v10; p[4]+=v11; p[5]+=v12;
            p[6]+=v20; p[7]+=v21; p[8]+=v22;
            pending = false;
            advance();
        }
        live = __syncthreads_count(pending ? 1 : 0);
    }

    // diagonal reduction
    d00=wave_reduce(d00); d01=wave_reduce(d01); d02=wave_reduce(d02);
    d10=wave_reduce(d10); d11=wave_reduce(d11); d12=wave_reduce(d12);
    d20=wave_reduce(d20); d21=wave_reduce(d21); d22=wave_reduce(d22);
    vsum=wave_reduce(vsum);
    if ((tid & 63) == 0) {
        int w = tid >> 6;
        dred[w*10+0]=d00; dred[w*10+1]=d01; dred[w*10+2]=d02;
        dred[w*10+3]=d10; dred[w*10+4]=d11; dred[w*10+5]=d12;
        dred[w*10+6]=d20; dred[w*10+7]=d21; dred[w*10+8]=d22;
        dred[w*10+9]=vsum;
    }
    __syncthreads();
    if (tid < 10) {
        float s = 0.f;
        for (int w = 0; w < 8; ++w) s += dred[w*10 + tid];
        dred[80 + tid] = s;
    }
    __syncthreads();
    if (tid < 9) val[9*r + tid] += dred[80 + tid];
    __syncthreads();

    // coalesced stores: output row i (global 3r+i), element k -> val[(k/3)*9 + i*3 + k%3]
    int q = n3 >> 2;   // float4 per row
    for (int k4 = tid; k4 < 3 * q; k4 += blockDim.x) {
        int i = (k4 >= q) + (k4 >= 2*q);
        int t4 = k4 - i * q;
        int kk = t4 << 2;
        float4 w;
        w.x = val[((kk+0)/3)*9 + i*3 + (kk+0)%3];
        w.y = val[((kk+1)/3)*9 + i*3 + (kk+1)%3];
        w.z = val[((kk+2)/3)*9 + i*3 + (kk+2)%3];
        w.w = val[((kk+3)/3)*9 + i*3 + (kk+3)%3];
        ((float4*)(Ks + (size_t)(3*r + i) * n3))[t4] = w;
    }
    if (tid < 3) {
        size_t d = (size_t)(3*r + tid);
        Ms[d * n3 + d] = rho * 0.25f * dred[89];
    }
}

// --------------------------- fallback scatter path ---------------------------
__global__ void __launch_bounds__(256)
fluid_assemble(const float* __restrict__ nodes, const int* __restrict__ elems,
               float* __restrict__ Kf, float* __restrict__ Mf, int nelem, int n)
{
    int e = blockIdx.x * blockDim.x + threadIdx.x;
    if (e >= nelem) return;
    const int4 nd = *reinterpret_cast<const int4*>(elems + 4ll * e);
    int ni[4] = { nd.x, nd.y, nd.z, nd.w };
    double g[4][3], vol;
    tet_grads(nodes, ni, g, vol);
#pragma unroll
    for (int a = 0; a < 4; ++a) {
        long long rowoff = (long long)ni[a] * n;
#pragma unroll
        for (int b = 0; b < 4; ++b) {
            double kv = vol * (g[a][0]*g[b][0] + g[a][1]*g[b][1] + g[a][2]*g[b][2]);
            double mv = vol * (a == b ? 0.3 : 0.1);
            atomicAdd(Kf + rowoff + ni[b], (float)kv);
            atomicAdd(Mf + rowoff + ni[b], (float)mv);
        }
    }
}

__global__ void __launch_bounds__(256)
solid_assemble(const float* __restrict__ nodes, const int* __restrict__ elems,
               float* __restrict__ Ks, float* __restrict__ Ms,
               const float* __restrict__ E_p, const float* __restrict__ nu_p,
               const float* __restrict__ rho_p, int nelem, int n3)
{
    int e = blockIdx.x * blockDim.x + threadIdx.x;
    if (e >= nelem) return;
    double E = (double)*E_p, nu = (double)*nu_p, rho = (double)*rho_p;
    double coeff = E / ((1.0 + nu) * (1.0 - 2.0 * nu));
    double lam = coeff * nu, mu = coeff * (1.0 - 2.0 * nu) * 0.5;
    const int4 nd = *reinterpret_cast<const int4*>(elems + 4ll * e);
    int ni[4] = { nd.x, nd.y, nd.z, nd.w };
    double g[4][3], vol;
    tet_grads(nodes, ni, g, vol);
    double lv = lam * vol, mv = mu * vol;
#pragma unroll
    for (int a = 0; a < 4; ++a) {
        long long row0 = 3ll * ni[a];
#pragma unroll
        for (int b = 0; b < 4; ++b) {
            long long col0 = 3ll * ni[b];
            double gg = g[a][0]*g[b][0] + g[a][1]*g[b][1] + g[a][2]*g[b][2];
#pragma unroll
            for (int i = 0; i < 3; ++i) {
                float* rowp = Ks + (row0 + i) * (long long)n3 + col0;
#pragma unroll
                for (int j = 0; j < 3; ++j) {
                    double val = lv * g[a][i] * g[b][j] + mv * g[a][j] * g[b][i];
                    if (i == j) val += mv * gg;
                    atomicAdd(rowp + j, (float)val);
                }
            }
        }
        float mval = (float)(rho * vol * 0.25);
#pragma unroll
        for (int i = 0; i < 3; ++i) {
            long long d = row0 + i;
            atomicAdd(Ms + d * (long long)n3 + d, mval);
        }
    }
}

// ---------------------------------------------------------------------------
extern "C" void kernel_launch(void* const* d_in, const int* in_sizes, int n_in,
                              void* d_out, int out_size, void* d_ws, size_t ws_size,
                              hipStream_t stream)
{
    const float* nodes = (const float*)d_in[0];
    const int*   fe    = (const int*)d_in[1];
    const int*   se    = (const int*)d_in[2];
    const float* E_p   = (const float*)d_in[3];
    const float* nu_p  = (const float*)d_in[4];
    const float* rho_p = (const float*)d_in[5];

    const int n  = in_sizes[0] / 3;
    const int nf = in_sizes[1] / 4;
    const int ns = in_sizes[2] / 4;
    const int n3 = 3 * n;

    float* out = (float*)d_out;
    float* Kf = out;
    float* Mf = Kf + (size_t)n * n;
    float* Ks = Mf + (size_t)n * n;
    float* Ms = Ks + (size_t)n3 * n3;

    size_t pos = 0;
    auto take = [&](size_t bytes) {
        size_t p = pos;
        pos = (pos + bytes + 255) & ~(size_t)255;
        return p;
    };
    size_t recF_o = take((size_t)nf * 64);
    size_t recS_o = take((size_t)ns * 64);
    size_t entF_o = take((size_t)4 * nf * 4);
    size_t entS_o = take((size_t)4 * ns * 4);
    size_t HF_o   = take((size_t)G_PART * n * 4);
    size_t HS_o   = take((size_t)G_PART * n * 4);
    size_t ints_o = take((size_t)(4 * n + 2) * 4);
    bool gather_ok = (pos <= ws_size);

    const int bs = 256;

    if (!gather_ok) {
        hipMemsetAsync(d_out, 0, (size_t)out_size * sizeof(float), stream);
        fluid_assemble<<<(nf + bs - 1) / bs, bs, 0, stream>>>(nodes, fe, Kf, Mf, nf, n);
        solid_assemble<<<(ns + bs - 1) / bs, bs, 0, stream>>>(nodes, se, Ks, Ms,
                                                              E_p, nu_p, rho_p, ns, n3);
        return;
    }

    char* ws = (char*)d_ws;
    float4* recF = (float4*)(ws + recF_o);
    float4* recS = (float4*)(ws + recS_o);
    int* entF = (int*)(ws + entF_o);
    int* entS = (int*)(ws + entS_o);
    int* HF   = (int*)(ws + HF_o);
    int* HS   = (int*)(ws + HS_o);
    int* ib   = (int*)(ws + ints_o);
    int* cntF = ib;
    int* cntS = ib + n;
    int* offF = ib + 2 * n;
    int* offS = ib + 3 * n + 1;

    const int4* fe4 = (const int4*)fe;
    const int4* se4 = (const int4*)se;

    // zero M_s (diagonal written by solid_gather; rest must be 0)
    hipMemsetAsync(Ms, 0, (size_t)n3 * n3 * sizeof(float), stream);

    geom_rec<<<(nf + bs - 1) / bs, bs, 0, stream>>>(nodes, fe4, recF, nf);
    geom_rec<<<(ns + bs - 1) / bs, bs, 0, stream>>>(nodes, se4, recS, ns);

    int chunkF = (nf + G_PART - 1) / G_PART;
    int chunkS = (ns + G_PART - 1) / G_PART;
    size_t histLds = (size_t)n * sizeof(int);
    hist_part<<<G_PART, bs, histLds, stream>>>(fe4, HF, nf, n, chunkF);
    hist_part<<<G_PART, bs, histLds, stream>>>(se4, HS, ns, n, chunkS);
    int csBlocks = (n + bs - 1) / bs;
    colscan<<<csBlocks, bs, 0, stream>>>(HF, cntF, n);
    colscan<<<csBlocks, bs, 0, stream>>>(HS, cntS, n);
    scan_two<<<2, bs, 0, stream>>>(cntF, cntS, offF, offS, n);
    scatter_part<<<G_PART, bs, histLds, stream>>>(fe4, HF, offF, entF, nf, n, chunkF);
    scatter_part<<<G_PART, bs, histLds, stream>>>(se4, HS, offS, entS, ns, n, chunkS);

    // gather-assemble (claim-arbitrated LDS accumulation)
    size_t fluidLds = (size_t)(2 * n) * 4 + (size_t)n * 2 + (16 + 2) * 4;
    size_t solidLds = (size_t)(9 * n) * 4 + (size_t)n * 2 + (80 + 10) * 4;
    fluid_gather<<<n, 512, fluidLds, stream>>>(entF, offF, recF, Kf, Mf, n);
    solid_gather<<<n, 512, solidLds, stream>>>(entS, offS, recS, Ks, Ms,
                                               E_p, nu_p, rho_p, n, n3);
}

// Round 6
// 251.348 us; speedup vs baseline: 15.4510x; 1.3770x over previous
//
#include <hip/hip_runtime.h>

// ---------------------------------------------------------------------------
// CoupledFEMSolver — fused gather assembly, geometry computed in-gather,
// claim-arbitrated LDS accumulation with FULLY PREFETCHED visits (no global
// loads inside the barrier loop), M_s folded into the solid store phase.
//
// Geometry per tet (double math; K entries ~ 1/det reach ~1e14):
//   det = r1.(r2 x r3); g1=(r2xr3)/det, g2=(r3xr1)/det, g3=(r1xr2)/det,
//   g0=-(g1+g2+g3); vol=|det|/6
// Fluid:  K_e[a][b] = vol*(ga.gb); M_e[a][b] = vol*(a==b ? .3 : .1)
// Solid:  K block (a,b) entry (i,j) =
//   vol*(lam*ga_i*gb_j + mu*ga_j*gb_i + (i==j)*mu*(ga.gb));
//   M_s diagonal only: rho*vol/4 per dof (3 rows/block written here too).
// Diagonal (b==a) contributions accumulate in registers + wave reduce.
// ---------------------------------------------------------------------------

#define G_PART 256

__device__ __forceinline__ float sel4(float x0, float x1, float x2, float x3, int a) {
    float r = x0;
    r = (a == 1) ? x1 : r;
    r = (a == 2) ? x2 : r;
    r = (a == 3) ? x3 : r;
    return r;
}
__device__ __forceinline__ int sel4i(int x0, int x1, int x2, int x3, int a) {
    int r = x0;
    r = (a == 1) ? x1 : r;
    r = (a == 2) ? x2 : r;
    r = (a == 3) ? x3 : r;
    return r;
}

__device__ __forceinline__ float wave_reduce(float v) {
#pragma unroll
    for (int m = 1; m < 64; m <<= 1) v += __shfl_xor(v, m, 64);
    return v;
}

// double-precision tet geometry -> f32 gradients g1..g3 and volume
__device__ __forceinline__ void tet_geom_f(const float* __restrict__ nodes,
                                           int n0, int n1, int n2, int n3_,
                                           float& gx1, float& gy1, float& gz1,
                                           float& gx2, float& gy2, float& gz2,
                                           float& gx3, float& gy3, float& gz3,
                                           float& volf)
{
    const float* q0 = nodes + 3ll * n0;
    const float* q1 = nodes + 3ll * n1;
    const float* q2 = nodes + 3ll * n2;
    const float* q3 = nodes + 3ll * n3_;
    double p0x = q0[0], p0y = q0[1], p0z = q0[2];
    double r1x = (double)q1[0] - p0x, r1y = (double)q1[1] - p0y, r1z = (double)q1[2] - p0z;
    double r2x = (double)q2[0] - p0x, r2y = (double)q2[1] - p0y, r2z = (double)q2[2] - p0z;
    double r3x = (double)q3[0] - p0x, r3y = (double)q3[1] - p0y, r3z = (double)q3[2] - p0z;
    double c23x = r2y*r3z - r2z*r3y, c23y = r2z*r3x - r2x*r3z, c23z = r2x*r3y - r2y*r3x;
    double det = r1x*c23x + r1y*c23y + r1z*c23z;
    double inv = 1.0 / det;
    double c31x = r3y*r1z - r3z*r1y, c31y = r3z*r1x - r3x*r1z, c31z = r3x*r1y - r3y*r1x;
    double c12x = r1y*r2z - r1z*r2y, c12y = r1z*r2x - r1x*r2z, c12z = r1x*r2y - r1y*r2x;
    gx1 = (float)(c23x*inv); gy1 = (float)(c23y*inv); gz1 = (float)(c23z*inv);
    gx2 = (float)(c31x*inv); gy2 = (float)(c31y*inv); gz2 = (float)(c31z*inv);
    gx3 = (float)(c12x*inv); gy3 = (float)(c12y*inv); gz3 = (float)(c12z*inv);
    volf = (float)(fabs(det) / 6.0);
}

// named-register visit state
#define DECL_VISIT(P) \
    float P##gx0=0,P##gx1=0,P##gx2=0,P##gx3=0, P##gy0=0,P##gy1=0,P##gy2=0,P##gy3=0, \
          P##gz0=0,P##gz1=0,P##gz2=0,P##gz3=0, P##vol=0, P##ga0=0,P##ga1=0,P##ga2=0; \
    int P##a=0, P##c0=0,P##c1=0,P##c2=0,P##c3=0;

#define LOAD_VISIT(P, ent, elems, idx) do { \
    int packed_ = (ent)[idx]; int e_ = packed_ >> 2; P##a = packed_ & 3; \
    int4 nd_ = (elems)[e_]; \
    P##c0 = nd_.x; P##c1 = nd_.y; P##c2 = nd_.z; P##c3 = nd_.w; \
    tet_geom_f(nodes, nd_.x, nd_.y, nd_.z, nd_.w, \
        P##gx1,P##gy1,P##gz1, P##gx2,P##gy2,P##gz2, P##gx3,P##gy3,P##gz3, P##vol); \
    P##gx0 = -(P##gx1+P##gx2+P##gx3); \
    P##gy0 = -(P##gy1+P##gy2+P##gy3); \
    P##gz0 = -(P##gz1+P##gz2+P##gz3); \
    P##ga0 = sel4(P##gx0,P##gx1,P##gx2,P##gx3,P##a); \
    P##ga1 = sel4(P##gy0,P##gy1,P##gy2,P##gy3,P##a); \
    P##ga2 = sel4(P##gz0,P##gz1,P##gz2,P##gz3,P##a); \
} while (0)

#define DIAG_S(P) do { \
    float lv_ = lam*P##vol, mv_ = mu*P##vol, lm_ = lv_+mv_; \
    float mgg_ = mv_*(P##ga0*P##ga0 + P##ga1*P##ga1 + P##ga2*P##ga2); \
    d00 += lm_*P##ga0*P##ga0 + mgg_; d01 += lm_*P##ga0*P##ga1;        d02 += lm_*P##ga0*P##ga2; \
    d10 += lm_*P##ga1*P##ga0;        d11 += lm_*P##ga1*P##ga1 + mgg_; d12 += lm_*P##ga1*P##ga2; \
    d20 += lm_*P##ga2*P##ga0;        d21 += lm_*P##ga2*P##ga1;        d22 += lm_*P##ga2*P##ga2 + mgg_; \
    vsum += P##vol; } while (0)

#define DIAG_F(P) do { \
    dK += P##vol*(P##ga0*P##ga0 + P##ga1*P##ga1 + P##ga2*P##ga2); \
    dM += P##vol*0.3f; } while (0)

#define PAIR_S(P, b_) do { \
    float gb0_ = sel4(P##gx0,P##gx1,P##gx2,P##gx3,b_); \
    float gb1_ = sel4(P##gy0,P##gy1,P##gy2,P##gy3,b_); \
    float gb2_ = sel4(P##gz0,P##gz1,P##gz2,P##gz3,b_); \
    col = sel4i(P##c0,P##c1,P##c2,P##c3,b_); \
    float lv_ = lam*P##vol, mv_ = mu*P##vol; \
    float la0_ = lv_*P##ga0, la1_ = lv_*P##ga1, la2_ = lv_*P##ga2; \
    float ma0_ = mv_*P##ga0, ma1_ = mv_*P##ga1, ma2_ = mv_*P##ga2; \
    float mgg_ = mv_*(P##ga0*gb0_ + P##ga1*gb1_ + P##ga2*gb2_); \
    v00 = la0_*gb0_ + ma0_*gb0_ + mgg_; v01 = la0_*gb1_ + ma1_*gb0_; v02 = la0_*gb2_ + ma2_*gb0_; \
    v10 = la1_*gb0_ + ma0_*gb1_; v11 = la1_*gb1_ + ma1_*gb1_ + mgg_; v12 = la1_*gb2_ + ma2_*gb1_; \
    v20 = la2_*gb0_ + ma0_*gb2_; v21 = la2_*gb1_ + ma1_*gb2_; v22 = la2_*gb2_ + ma2_*gb2_ + mgg_; \
} while (0)

#define PAIR_F(P, b_) do { \
    float gb0_ = sel4(P##gx0,P##gx1,P##gx2,P##gx3,b_); \
    float gb1_ = sel4(P##gy0,P##gy1,P##gy2,P##gy3,b_); \
    float gb2_ = sel4(P##gz0,P##gz1,P##gz2,P##gz3,b_); \
    col = sel4i(P##c0,P##c1,P##c2,P##c3,b_); \
    vK = P##vol*(P##ga0*gb0_ + P##ga1*gb1_ + P##ga2*gb2_); \
    vM = P##vol*0.1f; \
} while (0)

// --------------------- counting-sort inverted index (fused) -----------------
__global__ void __launch_bounds__(256)
hist_fused(const int4* __restrict__ fe, const int4* __restrict__ se,
           int* __restrict__ HF, int* __restrict__ HS,
           int nf, int ns, int n, int chunkF, int chunkS)
{
    extern __shared__ int h[];
    bool solid = blockIdx.x >= G_PART;
    int b = solid ? blockIdx.x - G_PART : blockIdx.x;
    const int4* elems = solid ? se : fe;
    int nelem = solid ? ns : nf;
    int chunk = solid ? chunkS : chunkF;
    int* H = solid ? HS : HF;

    for (int i = threadIdx.x; i < n; i += blockDim.x) h[i] = 0;
    __syncthreads();
    int beg = b * chunk, end = min(nelem, beg + chunk);
    for (int e = beg + threadIdx.x; e < end; e += blockDim.x) {
        int4 nd = elems[e];
        atomicAdd(&h[nd.x], 1);
        atomicAdd(&h[nd.y], 1);
        atomicAdd(&h[nd.z], 1);
        atomicAdd(&h[nd.w], 1);
    }
    __syncthreads();
    int* Hb = H + (size_t)b * n;
    for (int i = threadIdx.x; i < n; i += blockDim.x) Hb[i] = h[i];
}

__global__ void __launch_bounds__(256)
colscan_fused(int* __restrict__ HF, int* __restrict__ HS,
              int* __restrict__ cntF, int* __restrict__ cntS, int n)
{
    int gid = blockIdx.x * blockDim.x + threadIdx.x;
    if (gid >= 2 * n) return;
    bool solid = gid >= n;
    int node = solid ? gid - n : gid;
    int* H = solid ? HS : HF;
    int* cnt = solid ? cntS : cntF;
    int s = 0;
    for (int b = 0; b < G_PART; ++b) {
        size_t idx = (size_t)b * n + node;
        int v = H[idx];
        H[idx] = s;
        s += v;
    }
    cnt[node] = s;
}

__global__ void __launch_bounds__(256)
scan_two(const int* __restrict__ cntF, const int* __restrict__ cntS,
         int* __restrict__ offF, int* __restrict__ offS, int n)
{
    const int* cnt = blockIdx.x ? cntS : cntF;
    int* off = blockIdx.x ? offS : offF;
    __shared__ int partial[256];
    int t = threadIdx.x;
    int ch = (n + 255) / 256;
    int base = t * ch;
    int s = 0;
    for (int k = 0; k < ch; ++k) {
        int i = base + k;
        if (i < n) s += cnt[i];
    }
    partial[t] = s;
    __syncthreads();
    for (int d = 1; d < 256; d <<= 1) {
        int v = (t >= d) ? partial[t - d] : 0;
        __syncthreads();
        partial[t] += v;
        __syncthreads();
    }
    int run = (t == 0) ? 0 : partial[t - 1];
    for (int k = 0; k < ch; ++k) {
        int i = base + k;
        if (i < n) { off[i] = run; run += cnt[i]; }
    }
    if (t == 255) off[n] = partial[255];
}

__global__ void __launch_bounds__(256)
scatter_fused(const int4* __restrict__ fe, const int4* __restrict__ se,
              const int* __restrict__ HF, const int* __restrict__ HS,
              const int* __restrict__ offF, const int* __restrict__ offS,
              int* __restrict__ entF, int* __restrict__ entS,
              int nf, int ns, int n, int chunkF, int chunkS)
{
    extern __shared__ int slot[];
    bool solid = blockIdx.x >= G_PART;
    int b = solid ? blockIdx.x - G_PART : blockIdx.x;
    const int4* elems = solid ? se : fe;
    int nelem = solid ? ns : nf;
    int chunk = solid ? chunkS : chunkF;
    const int* H = solid ? HS : HF;
    const int* off = solid ? offS : offF;
    int* entries = solid ? entS : entF;

    const int* Hb = H + (size_t)b * n;
    for (int i = threadIdx.x; i < n; i += blockDim.x)
        slot[i] = off[i] + Hb[i];
    __syncthreads();
    int beg = b * chunk, end = min(nelem, beg + chunk);
    for (int e = beg + threadIdx.x; e < end; e += blockDim.x) {
        int4 nd = elems[e];
        int p;
        p = atomicAdd(&slot[nd.x], 1); entries[p] = e * 4 + 0;
        p = atomicAdd(&slot[nd.y], 1); entries[p] = e * 4 + 1;
        p = atomicAdd(&slot[nd.z], 1); entries[p] = e * 4 + 2;
        p = atomicAdd(&slot[nd.w], 1); entries[p] = e * 4 + 3;
    }
}

// ------------------------------ fused gather --------------------------------
// blocks [0,n): solid node rows (3 x 3n in LDS + Ms rows); [n,2n): fluid rows.
__global__ void __launch_bounds__(512, 4)
fused_gather(const int* __restrict__ entF, const int* __restrict__ offF,
             const int* __restrict__ entS, const int* __restrict__ offS,
             const int4* __restrict__ fe, const int4* __restrict__ se,
             const float* __restrict__ nodes,
             float* __restrict__ Kf, float* __restrict__ Mf,
             float* __restrict__ Ks, float* __restrict__ Ms,
             const float* __restrict__ E_p, const float* __restrict__ nu_p,
             const float* __restrict__ rho_p, int n, int n3)
{
    extern __shared__ unsigned char smem[];
    const int tid = threadIdx.x;
    const int bid = blockIdx.x;

    if (bid < n) {
        // ================= solid =================
        const int r = bid;
        float* val = (float*)smem;                               // 9n floats
        unsigned short* claim = (unsigned short*)(val + 9 * n);  // n
        float* dred = (float*)(claim + n);                       // 90 floats

        {
            float4* v = (float4*)val;
            int cnt = (9 * n) >> 2;
            for (int k = tid; k < cnt; k += 512) v[k] = make_float4(0.f,0.f,0.f,0.f);
        }

        float E = *E_p, nu = *nu_p, rho = *rho_p;
        float coeff = E / ((1.f + nu) * (1.f - 2.f * nu));
        float lam = coeff * nu;
        float mu  = coeff * (1.f - 2.f * nu) * 0.5f;

        const int beg = offS[r], end = offS[r + 1];

        float d00=0,d01=0,d02=0,d10=0,d11=0,d12=0,d20=0,d21=0,d22=0,vsum=0;
        DECL_VISIT(A_);
        DECL_VISIT(B_);

        bool pending = false, validB = false;
        int s, col = 0, nextIdx = beg + tid + 1024;
        float v00=0,v01=0,v02=0,v10=0,v11=0,v12=0,v20=0,v21=0,v22=0;

        const int idx0 = beg + tid, idx1 = idx0 + 512;
        if (idx0 < end) { LOAD_VISIT(A_, entS, se, idx0); DIAG_S(A_); s = 0; }
        else s = 6;
        if (idx1 < end) { LOAD_VISIT(B_, entS, se, idx1); DIAG_S(B_); validB = true; }

        auto advanceS = [&]() {
            while (!pending) {
                if (s >= 6 || (s >= 3 && !validB)) {
                    if (nextIdx >= end) return;
                    LOAD_VISIT(B_, entS, se, nextIdx);   // rare tail (row >1024)
                    DIAG_S(B_);
                    validB = true; nextIdx += 512; s = 3;
                }
                if (s < 3) { int t = s;     int b_ = t + (t >= A_a ? 1 : 0); PAIR_S(A_, b_); }
                else       { int t = s - 3; int b_ = t + (t >= B_a ? 1 : 0); PAIR_S(B_, b_); }
                ++s; pending = true;
            }
        };

        advanceS();
        int live = __syncthreads_count(pending ? 1 : 0);
        while (live) {
            if (pending) claim[col] = (unsigned short)tid;
            __syncthreads();
            if (pending && claim[col] == (unsigned short)tid) {
                float* p = val + 9 * col;
                p[0]+=v00; p[1]+=v01; p[2]+=v02;
                p[3]+=v10; p[4]+=v11; p[5]+=v12;
                p[6]+=v20; p[7]+=v21; p[8]+=v22;
                pending = false;
                advanceS();
            }
            live = __syncthreads_count(pending ? 1 : 0);
        }

        // diagonal reduction
        d00=wave_reduce(d00); d01=wave_reduce(d01); d02=wave_reduce(d02);
        d10=wave_reduce(d10); d11=wave_reduce(d11); d12=wave_reduce(d12);
        d20=wave_reduce(d20); d21=wave_reduce(d21); d22=wave_reduce(d22);
        vsum=wave_reduce(vsum);
        if ((tid & 63) == 0) {
            int w = tid >> 6;
            dred[w*10+0]=d00; dred[w*10+1]=d01; dred[w*10+2]=d02;
            dred[w*10+3]=d10; dred[w*10+4]=d11; dred[w*10+5]=d12;
            dred[w*10+6]=d20; dred[w*10+7]=d21; dred[w*10+8]=d22;
            dred[w*10+9]=vsum;
        }
        __syncthreads();
        if (tid < 10) {
            float t = 0.f;
            for (int w = 0; w < 8; ++w) t += dred[w*10 + tid];
            dred[80 + tid] = t;
        }
        __syncthreads();
        if (tid < 9) val[9*r + tid] += dred[80 + tid];
        __syncthreads();

        // Ks rows 3r..3r+2 (contiguous), transposed out of [col][9] layout
        int q = n3 >> 2;
        for (int k4 = tid; k4 < 3 * q; k4 += 512) {
            int i = (k4 >= q) + (k4 >= 2*q);
            int t4 = k4 - i * q;
            int kk = t4 << 2;
            float4 w;
            w.x = val[((kk+0)/3)*9 + i*3 + (kk+0)%3];
            w.y = val[((kk+1)/3)*9 + i*3 + (kk+1)%3];
            w.z = val[((kk+2)/3)*9 + i*3 + (kk+2)%3];
            w.w = val[((kk+3)/3)*9 + i*3 + (kk+3)%3];
            ((float4*)(Ks + (size_t)(3*r + i) * n3))[t4] = w;
        }
        // Ms rows: zeros + diagonal (folded memset)
        float diag = rho * 0.25f * dred[89];
        for (int k4 = tid; k4 < 3 * q; k4 += 512) {
            int i = (k4 >= q) + (k4 >= 2*q);
            int t4 = k4 - i * q;
            int dcol = 3*r + i;
            int base = t4 << 2;
            float4 w;
            w.x = (base + 0 == dcol) ? diag : 0.f;
            w.y = (base + 1 == dcol) ? diag : 0.f;
            w.z = (base + 2 == dcol) ? diag : 0.f;
            w.w = (base + 3 == dcol) ? diag : 0.f;
            ((float4*)(Ms + (size_t)(3*r + i) * n3))[t4] = w;
        }
    } else {
        // ================= fluid =================
        const int r = bid - n;
        float* val = (float*)smem;                               // 2n: [col]{K,M}
        unsigned short* claim = (unsigned short*)(val + 2 * n);  // n
        float* dred = (float*)(claim + n);                       // 18 floats

        {
            float4* v = (float4*)val;
            int cnt = (2 * n) >> 2;
            for (int k = tid; k < cnt; k += 512) v[k] = make_float4(0.f,0.f,0.f,0.f);
        }

        const int beg = offF[r], end = offF[r + 1];

        float dK = 0.f, dM = 0.f;
        DECL_VISIT(A_);
        DECL_VISIT(B_);

        bool pending = false, validB = false;
        int s, col = 0, nextIdx = beg + tid + 1024;
        float vK = 0.f, vM = 0.f;

        const int idx0 = beg + tid, idx1 = idx0 + 512;
        if (idx0 < end) { LOAD_VISIT(A_, entF, fe, idx0); DIAG_F(A_); s = 0; }
        else s = 6;
        if (idx1 < end) { LOAD_VISIT(B_, entF, fe, idx1); DIAG_F(B_); validB = true; }

        auto advanceF = [&]() {
            while (!pending) {
                if (s >= 6 || (s >= 3 && !validB)) {
                    if (nextIdx >= end) return;
                    LOAD_VISIT(B_, entF, fe, nextIdx);
                    DIAG_F(B_);
                    validB = true; nextIdx += 512; s = 3;
                }
                if (s < 3) { int t = s;     int b_ = t + (t >= A_a ? 1 : 0); PAIR_F(A_, b_); }
                else       { int t = s - 3; int b_ = t + (t >= B_a ? 1 : 0); PAIR_F(B_, b_); }
                ++s; pending = true;
            }
        };

        advanceF();
        int live = __syncthreads_count(pending ? 1 : 0);
        while (live) {
            if (pending) claim[col] = (unsigned short)tid;
            __syncthreads();
            if (pending && claim[col] == (unsigned short)tid) {
                float2* p = (float2*)(val + 2 * col);
                float2 t = *p;
                t.x += vK; t.y += vM;
                *p = t;
                pending = false;
                advanceF();
            }
            live = __syncthreads_count(pending ? 1 : 0);
        }

        dK = wave_reduce(dK);
        dM = wave_reduce(dM);
        if ((tid & 63) == 0) { int w = tid >> 6; dred[w*2+0] = dK; dred[w*2+1] = dM; }
        __syncthreads();
        if (tid < 2) {
            float t = 0.f;
            for (int w = 0; w < 8; ++w) t += dred[w*2 + tid];
            dred[16 + tid] = t;
        }
        __syncthreads();
        if (tid == 0) { val[2*r] += dred[16]; val[2*r+1] += dred[17]; }
        __syncthreads();

        size_t rowoff = (size_t)r * n;
        int qf = n >> 2;
        float4* K4 = (float4*)(Kf + rowoff);
        float4* M4 = (float4*)(Mf + rowoff);
        for (int c4 = tid; c4 < qf; c4 += 512) {
            int c = c4 << 2;
            K4[c4] = make_float4(val[2*c],   val[2*(c+1)],   val[2*(c+2)],   val[2*(c+3)]);
            M4[c4] = make_float4(val[2*c+1], val[2*(c+1)+1], val[2*(c+2)+1], val[2*(c+3)+1]);
        }
    }
}

// --------------------------- fallback scatter path ---------------------------
__device__ __forceinline__ void tet_grads_d(const float* __restrict__ nodes,
                                            const int* ni, double g[4][3], double& vol)
{
    double p[4][3];
#pragma unroll
    for (int a = 0; a < 4; ++a) {
        const float* q = nodes + 3ll * ni[a];
        p[a][0] = (double)q[0]; p[a][1] = (double)q[1]; p[a][2] = (double)q[2];
    }
    double r1[3], r2[3], r3[3];
#pragma unroll
    for (int k = 0; k < 3; ++k) {
        r1[k] = p[1][k] - p[0][k];
        r2[k] = p[2][k] - p[0][k];
        r3[k] = p[3][k] - p[0][k];
    }
    double c23[3] = { r2[1]*r3[2]-r2[2]*r3[1], r2[2]*r3[0]-r2[0]*r3[2], r2[0]*r3[1]-r2[1]*r3[0] };
    double det = r1[0]*c23[0] + r1[1]*c23[1] + r1[2]*c23[2];
    double inv = 1.0 / det;
    double c31[3] = { r3[1]*r1[2]-r3[2]*r1[1], r3[2]*r1[0]-r3[0]*r1[2], r3[0]*r1[1]-r3[1]*r1[0] };
    double c12[3] = { r1[1]*r2[2]-r1[2]*r2[1], r1[2]*r2[0]-r1[0]*r2[2], r1[0]*r2[1]-r1[1]*r2[0] };
#pragma unroll
    for (int k = 0; k < 3; ++k) {
        g[1][k] = c23[k]*inv; g[2][k] = c31[k]*inv; g[3][k] = c12[k]*inv;
        g[0][k] = -(g[1][k] + g[2][k] + g[3][k]);
    }
    vol = fabs(det) / 6.0;
}

__global__ void __launch_bounds__(256)
fluid_assemble(const float* __restrict__ nodes, const int* __restrict__ elems,
               float* __restrict__ Kf, float* __restrict__ Mf, int nelem, int n)
{
    int e = blockIdx.x * blockDim.x + threadIdx.x;
    if (e >= nelem) return;
    const int4 nd = *reinterpret_cast<const int4*>(elems + 4ll * e);
    int ni[4] = { nd.x, nd.y, nd.z, nd.w };
    double g[4][3], vol;
    tet_grads_d(nodes, ni, g, vol);
#pragma unroll
    for (int a = 0; a < 4; ++a) {
        long long rowoff = (long long)ni[a] * n;
#pragma unroll
        for (int b = 0; b < 4; ++b) {
            double kv = vol * (g[a][0]*g[b][0] + g[a][1]*g[b][1] + g[a][2]*g[b][2]);
            double mv = vol * (a == b ? 0.3 : 0.1);
            atomicAdd(Kf + rowoff + ni[b], (float)kv);
            atomicAdd(Mf + rowoff + ni[b], (float)mv);
        }
    }
}

__global__ void __launch_bounds__(256)
solid_assemble(const float* __restrict__ nodes, const int* __restrict__ elems,
               float* __restrict__ Ks, float* __restrict__ Ms,
               const float* __restrict__ E_p, const float* __restrict__ nu_p,
               const float* __restrict__ rho_p, int nelem, int n3)
{
    int e = blockIdx.x * blockDim.x + threadIdx.x;
    if (e >= nelem) return;
    double E = (double)*E_p, nu = (double)*nu_p, rho = (double)*rho_p;
    double coeff = E / ((1.0 + nu) * (1.0 - 2.0 * nu));
    double lam = coeff * nu, mu = coeff * (1.0 - 2.0 * nu) * 0.5;
    const int4 nd = *reinterpret_cast<const int4*>(elems + 4ll * e);
    int ni[4] = { nd.x, nd.y, nd.z, nd.w };
    double g[4][3], vol;
    tet_grads_d(nodes, ni, g, vol);
    double lv = lam * vol, mv = mu * vol;
#pragma unroll
    for (int a = 0; a < 4; ++a) {
        long long row0 = 3ll * ni[a];
#pragma unroll
        for (int b = 0; b < 4; ++b) {
            long long col0 = 3ll * ni[b];
            double gg = g[a][0]*g[b][0] + g[a][1]*g[b][1] + g[a][2]*g[b][2];
#pragma unroll
            for (int i = 0; i < 3; ++i) {
                float* rowp = Ks + (row0 + i) * (long long)n3 + col0;
#pragma unroll
                for (int j = 0; j < 3; ++j) {
                    double val = lv * g[a][i] * g[b][j] + mv * g[a][j] * g[b][i];
                    if (i == j) val += mv * gg;
                    atomicAdd(rowp + j, (float)val);
                }
            }
        }
        float mval = (float)(rho * vol * 0.25);
#pragma unroll
        for (int i = 0; i < 3; ++i) {
            long long d = row0 + i;
            atomicAdd(Ms + d * (long long)n3 + d, mval);
        }
    }
}

// ---------------------------------------------------------------------------
extern "C" void kernel_launch(void* const* d_in, const int* in_sizes, int n_in,
                              void* d_out, int out_size, void* d_ws, size_t ws_size,
                              hipStream_t stream)
{
    const float* nodes = (const float*)d_in[0];
    const int*   fe    = (const int*)d_in[1];
    const int*   se    = (const int*)d_in[2];
    const float* E_p   = (const float*)d_in[3];
    const float* nu_p  = (const float*)d_in[4];
    const float* rho_p = (const float*)d_in[5];

    const int n  = in_sizes[0] / 3;
    const int nf = in_sizes[1] / 4;
    const int ns = in_sizes[2] / 4;
    const int n3 = 3 * n;

    float* out = (float*)d_out;
    float* Kf = out;
    float* Mf = Kf + (size_t)n * n;
    float* Ks = Mf + (size_t)n * n;
    float* Ms = Ks + (size_t)n3 * n3;

    size_t pos = 0;
    auto take = [&](size_t bytes) {
        size_t p = pos;
        pos = (pos + bytes + 255) & ~(size_t)255;
        return p;
    };
    size_t entF_o = take((size_t)4 * nf * 4);
    size_t entS_o = take((size_t)4 * ns * 4);
    size_t HF_o   = take((size_t)G_PART * n * 4);
    size_t HS_o   = take((size_t)G_PART * n * 4);
    size_t ints_o = take((size_t)(4 * n + 2) * 4);
    bool gather_ok = (pos <= ws_size) && ((n & 3) == 0);

    const int bs = 256;

    if (!gather_ok) {
        hipMemsetAsync(d_out, 0, (size_t)out_size * sizeof(float), stream);
        fluid_assemble<<<(nf + bs - 1) / bs, bs, 0, stream>>>(nodes, fe, Kf, Mf, nf, n);
        solid_assemble<<<(ns + bs - 1) / bs, bs, 0, stream>>>(nodes, se, Ks, Ms,
                                                              E_p, nu_p, rho_p, ns, n3);
        return;
    }

    char* ws = (char*)d_ws;
    int* entF = (int*)(ws + entF_o);
    int* entS = (int*)(ws + entS_o);
    int* HF   = (int*)(ws + HF_o);
    int* HS   = (int*)(ws + HS_o);
    int* ib   = (int*)(ws + ints_o);
    int* cntF = ib;
    int* cntS = ib + n;
    int* offF = ib + 2 * n;
    int* offS = ib + 3 * n + 1;

    const int4* fe4 = (const int4*)fe;
    const int4* se4 = (const int4*)se;

    int chunkF = (nf + G_PART - 1) / G_PART;
    int chunkS = (ns + G_PART - 1) / G_PART;
    size_t histLds = (size_t)n * sizeof(int);

    hist_fused<<<2 * G_PART, bs, histLds, stream>>>(fe4, se4, HF, HS,
                                                    nf, ns, n, chunkF, chunkS);
    colscan_fused<<<(2 * n + bs - 1) / bs, bs, 0, stream>>>(HF, HS, cntF, cntS, n);
    scan_two<<<2, bs, 0, stream>>>(cntF, cntS, offF, offS, n);
    scatter_fused<<<2 * G_PART, bs, histLds, stream>>>(fe4, se4, HF, HS, offF, offS,
                                                       entF, entS, nf, ns, n, chunkF, chunkS);

    size_t gatherLds = (size_t)9 * n * 4 + (size_t)n * 2 + 96 * 4;
    fused_gather<<<2 * n, 512, gatherLds, stream>>>(entF, offF, entS, offS,
                                                    fe4, se4, nodes,
                                                    Kf, Mf, Ks, Ms,
                                                    E_p, nu_p, rho_p, n, n3);
}

// Round 7
// 199.577 us; speedup vs baseline: 19.4591x; 1.2594x over previous
//
#include <hip/hip_runtime.h>

// ---------------------------------------------------------------------------
// CoupledFEMSolver — fused gather assembly v2.
//   * ONE index kernel: per-partition LDS hist -> block-local exclusive scan
//     -> per-partition prefix P[b][0..n] -> partition-contiguous entry lists.
//     (replaces hist/colscan/scan/scatter chain; no H round-trips)
//   * Gather: per-row partition ranges from P; wave-scan of 256 counts -> Q;
//     visits located by 8-step binary search (prologue only, fully prefetched);
//     claim-arbitrated PLAIN-write LDS accumulation (no LDS atomic RMW);
//     PLANE-MAJOR accumulators so stores are contiguous b128 reads;
//     diagonal block in registers + wave reduce; M_s written inline.
//
// Geometry per tet (double math; K entries ~ 1/det reach ~1e14):
//   det = r1.(r2 x r3); g1=(r2xr3)/det, g2=(r3xr1)/det, g3=(r1xr2)/det,
//   g0=-(g1+g2+g3); vol=|det|/6
// Fluid:  K_e[a][b] = vol*(ga.gb); M_e[a][b] = vol*(a==b ? .3 : .1)
// Solid:  K block (a,b) entry (i,j) =
//   vol*(lam*ga_i*gb_j + mu*ga_j*gb_i + (i==j)*mu*(ga.gb));
//   M_s diagonal only: rho*vol/4 per dof.
// ---------------------------------------------------------------------------

#define G_PART 256

__device__ __forceinline__ float sel4(float x0, float x1, float x2, float x3, int a) {
    float r = x0;
    r = (a == 1) ? x1 : r;
    r = (a == 2) ? x2 : r;
    r = (a == 3) ? x3 : r;
    return r;
}
__device__ __forceinline__ int sel4i(int x0, int x1, int x2, int x3, int a) {
    int r = x0;
    r = (a == 1) ? x1 : r;
    r = (a == 2) ? x2 : r;
    r = (a == 3) ? x3 : r;
    return r;
}

__device__ __forceinline__ float wave_reduce(float v) {
#pragma unroll
    for (int m = 1; m < 64; m <<= 1) v += __shfl_xor(v, m, 64);
    return v;
}

// double-precision tet geometry -> f32 gradients g1..g3 and volume
__device__ __forceinline__ void tet_geom_f(const float* __restrict__ nodes,
                                           int n0, int n1, int n2, int n3_,
                                           float& gx1, float& gy1, float& gz1,
                                           float& gx2, float& gy2, float& gz2,
                                           float& gx3, float& gy3, float& gz3,
                                           float& volf)
{
    const float* q0 = nodes + 3ll * n0;
    const float* q1 = nodes + 3ll * n1;
    const float* q2 = nodes + 3ll * n2;
    const float* q3 = nodes + 3ll * n3_;
    double p0x = q0[0], p0y = q0[1], p0z = q0[2];
    double r1x = (double)q1[0] - p0x, r1y = (double)q1[1] - p0y, r1z = (double)q1[2] - p0z;
    double r2x = (double)q2[0] - p0x, r2y = (double)q2[1] - p0y, r2z = (double)q2[2] - p0z;
    double r3x = (double)q3[0] - p0x, r3y = (double)q3[1] - p0y, r3z = (double)q3[2] - p0z;
    double c23x = r2y*r3z - r2z*r3y, c23y = r2z*r3x - r2x*r3z, c23z = r2x*r3y - r2y*r3x;
    double det = r1x*c23x + r1y*c23y + r1z*c23z;
    double inv = 1.0 / det;
    double c31x = r3y*r1z - r3z*r1y, c31y = r3z*r1x - r3x*r1z, c31z = r3x*r1y - r3y*r1x;
    double c12x = r1y*r2z - r1z*r2y, c12y = r1z*r2x - r1x*r2z, c12z = r1x*r2y - r1y*r2x;
    gx1 = (float)(c23x*inv); gy1 = (float)(c23y*inv); gz1 = (float)(c23z*inv);
    gx2 = (float)(c31x*inv); gy2 = (float)(c31y*inv); gz2 = (float)(c31z*inv);
    gx3 = (float)(c12x*inv); gy3 = (float)(c12y*inv); gz3 = (float)(c12z*inv);
    volf = (float)(fabs(det) / 6.0);
}

// visit packed-entry -> partition lookup: exactly 8 bisection steps over 256
__device__ __forceinline__ int fetch_entry(const int* __restrict__ ent,
                                           const int* __restrict__ Sb,
                                           const int* __restrict__ Qb,
                                           int chunk4, int v)
{
    int lo = 0, hi = 255;
#pragma unroll
    for (int it = 0; it < 8; ++it) {
        int mid = (lo + hi + 1) >> 1;
        bool ge = (Qb[mid] <= v);
        lo = ge ? mid : lo;
        hi = ge ? hi : mid - 1;
    }
    return ent[(size_t)lo * chunk4 + Sb[lo] + (v - Qb[lo])];
}

// named-register visit state
#define DECL_VISIT(P) \
    float P##gx0=0,P##gx1=0,P##gx2=0,P##gx3=0, P##gy0=0,P##gy1=0,P##gy2=0,P##gy3=0, \
          P##gz0=0,P##gz1=0,P##gz2=0,P##gz3=0, P##vol=0, P##ga0=0,P##ga1=0,P##ga2=0; \
    int P##a=0, P##c0=0,P##c1=0,P##c2=0,P##c3=0;

#define LOAD_VISIT(P, packed_) do { \
    int e_ = (packed_) >> 2; P##a = (packed_) & 3; \
    int4 nd_ = elems4[e_]; \
    P##c0 = nd_.x; P##c1 = nd_.y; P##c2 = nd_.z; P##c3 = nd_.w; \
    tet_geom_f(nodes, nd_.x, nd_.y, nd_.z, nd_.w, \
        P##gx1,P##gy1,P##gz1, P##gx2,P##gy2,P##gz2, P##gx3,P##gy3,P##gz3, P##vol); \
    P##gx0 = -(P##gx1+P##gx2+P##gx3); \
    P##gy0 = -(P##gy1+P##gy2+P##gy3); \
    P##gz0 = -(P##gz1+P##gz2+P##gz3); \
    P##ga0 = sel4(P##gx0,P##gx1,P##gx2,P##gx3,P##a); \
    P##ga1 = sel4(P##gy0,P##gy1,P##gy2,P##gy3,P##a); \
    P##ga2 = sel4(P##gz0,P##gz1,P##gz2,P##gz3,P##a); \
} while (0)

#define DIAG_S(P) do { \
    float lv_ = lam*P##vol, mv_ = mu*P##vol, lm_ = lv_+mv_; \
    float mgg_ = mv_*(P##ga0*P##ga0 + P##ga1*P##ga1 + P##ga2*P##ga2); \
    d00 += lm_*P##ga0*P##ga0 + mgg_; d01 += lm_*P##ga0*P##ga1;        d02 += lm_*P##ga0*P##ga2; \
    d10 += lm_*P##ga1*P##ga0;        d11 += lm_*P##ga1*P##ga1 + mgg_; d12 += lm_*P##ga1*P##ga2; \
    d20 += lm_*P##ga2*P##ga0;        d21 += lm_*P##ga2*P##ga1;        d22 += lm_*P##ga2*P##ga2 + mgg_; \
    vsum += P##vol; } while (0)

#define DIAG_F(P) do { \
    dK += P##vol*(P##ga0*P##ga0 + P##ga1*P##ga1 + P##ga2*P##ga2); \
    dM += P##vol*0.3f; } while (0)

#define PAIR_S(P, b_) do { \
    float gb0_ = sel4(P##gx0,P##gx1,P##gx2,P##gx3,b_); \
    float gb1_ = sel4(P##gy0,P##gy1,P##gy2,P##gy3,b_); \
    float gb2_ = sel4(P##gz0,P##gz1,P##gz2,P##gz3,b_); \
    col = sel4i(P##c0,P##c1,P##c2,P##c3,b_); \
    float lv_ = lam*P##vol, mv_ = mu*P##vol; \
    float la0_ = lv_*P##ga0, la1_ = lv_*P##ga1, la2_ = lv_*P##ga2; \
    float ma0_ = mv_*P##ga0, ma1_ = mv_*P##ga1, ma2_ = mv_*P##ga2; \
    float mgg_ = mv_*(P##ga0*gb0_ + P##ga1*gb1_ + P##ga2*gb2_); \
    v00 = la0_*gb0_ + ma0_*gb0_ + mgg_; v01 = la0_*gb1_ + ma1_*gb0_; v02 = la0_*gb2_ + ma2_*gb0_; \
    v10 = la1_*gb0_ + ma0_*gb1_; v11 = la1_*gb1_ + ma1_*gb1_ + mgg_; v12 = la1_*gb2_ + ma2_*gb1_; \
    v20 = la2_*gb0_ + ma0_*gb2_; v21 = la2_*gb1_ + ma1_*gb2_; v22 = la2_*gb2_ + ma2_*gb2_ + mgg_; \
} while (0)

#define PAIR_F(P, b_) do { \
    float gb0_ = sel4(P##gx0,P##gx1,P##gx2,P##gx3,b_); \
    float gb1_ = sel4(P##gy0,P##gy1,P##gy2,P##gy3,b_); \
    float gb2_ = sel4(P##gz0,P##gz1,P##gz2,P##gz3,b_); \
    col = sel4i(P##c0,P##c1,P##c2,P##c3,b_); \
    vK = P##vol*(P##ga0*gb0_ + P##ga1*gb1_ + P##ga2*gb2_); \
    vM = P##vol*0.1f; \
} while (0)

// ------------------- one-kernel partition-local index build ------------------
// block b: LDS hist of chunk -> block exclusive scan -> P[b][0..n] ->
// place entries into ent + b*4*chunk (partition-contiguous, grouped by node).
__global__ void __launch_bounds__(256)
index_build(const int4* __restrict__ fe, const int4* __restrict__ se,
            int* __restrict__ entF, int* __restrict__ entS,
            int* __restrict__ PF, int* __restrict__ PS,
            int nf, int ns, int n, int chunkF, int chunkS)
{
    extern __shared__ int h[];            // n + 256
    int* wsum = h + n;
    const bool solid = blockIdx.x >= G_PART;
    const int b = solid ? blockIdx.x - G_PART : blockIdx.x;
    const int4* elems = solid ? se : fe;
    const int nelem = solid ? ns : nf;
    const int chunk = solid ? chunkS : chunkF;
    int* P = (solid ? PS : PF) + (size_t)b * (n + 1);
    int* entries = (solid ? entS : entF) + (size_t)b * 4 * chunk;

    const int t = threadIdx.x;
    const int beg = b * chunk, end = min(nelem, beg + chunk);

    for (int i = t; i < n; i += 256) h[i] = 0;
    __syncthreads();
    for (int e = beg + t; e < end; e += 256) {
        int4 nd = elems[e];
        atomicAdd(&h[nd.x], 1);
        atomicAdd(&h[nd.y], 1);
        atomicAdd(&h[nd.z], 1);
        atomicAdd(&h[nd.w], 1);
    }
    __syncthreads();

    // block exclusive scan of h[0..n)
    const int cs = (n + 255) / 256;
    const int base = t * cs;
    int s = 0;
    for (int k = 0; k < cs; ++k) {
        int i = base + k;
        if (i < n) s += h[i];
    }
    wsum[t] = s;
    __syncthreads();
    for (int d = 1; d < 256; d <<= 1) {
        int v = (t >= d) ? wsum[t - d] : 0;
        __syncthreads();
        wsum[t] += v;
        __syncthreads();
    }
    int run = (t == 0) ? 0 : wsum[t - 1];
    for (int k = 0; k < cs; ++k) {
        int i = base + k;
        if (i < n) { int c = h[i]; h[i] = run; P[i] = run; run += c; }
    }
    if (t == 255) P[n] = wsum[255];
    __syncthreads();

    // place entries (h[] now holds cursors = prefix)
    for (int e = beg + t; e < end; e += 256) {
        int4 nd = elems[e];
        int p;
        p = atomicAdd(&h[nd.x], 1); entries[p] = e * 4 + 0;
        p = atomicAdd(&h[nd.y], 1); entries[p] = e * 4 + 1;
        p = atomicAdd(&h[nd.z], 1); entries[p] = e * 4 + 2;
        p = atomicAdd(&h[nd.w], 1); entries[p] = e * 4 + 3;
    }
}

// ------------------------------ fused gather --------------------------------
// blocks [0,n): solid node rows; [n,2n): fluid rows.
__global__ void __launch_bounds__(512, 4)
fused_gather(const int* __restrict__ entF, const int* __restrict__ PF,
             const int* __restrict__ entS, const int* __restrict__ PS,
             const int4* __restrict__ fe, const int4* __restrict__ se,
             const float* __restrict__ nodes,
             float* __restrict__ Kf, float* __restrict__ Mf,
             float* __restrict__ Ks, float* __restrict__ Ms,
             const float* __restrict__ E_p, const float* __restrict__ nu_p,
             const float* __restrict__ rho_p, int n, int n3,
             int chunk4F, int chunk4S)
{
    extern __shared__ unsigned char smem[];
    const int tid = threadIdx.x;
    const int bid = blockIdx.x;

    if (bid < n) {
        // ================= solid =================
        const int r = bid;
        const int4* elems4 = se;
        float* val = (float*)smem;                               // 9n (3 planes of n3)
        unsigned short* claim = (unsigned short*)(val + 9 * n);  // n
        int* Sb = (int*)(claim + n);                             // 256
        int* Qb = Sb + 256;                                      // 257
        float* dred = (float*)(Qb + 257);                        // 90

        {
            float4* v = (float4*)val;
            int cnt = (9 * n) >> 2;
            for (int k = tid; k < cnt; k += 512) v[k] = make_float4(0.f,0.f,0.f,0.f);
        }
        if (tid < 256) {
            const int* Pp = PS + (size_t)tid * (n + 1) + r;
            int s0 = Pp[0], e0 = Pp[1];
            Sb[tid] = s0;
            Qb[tid] = e0 - s0;     // counts, scanned below
        }
        __syncthreads();
        if (tid < 64) {
            int c0 = Qb[4*tid], c1 = Qb[4*tid+1], c2 = Qb[4*tid+2], c3 = Qb[4*tid+3];
            int s = c0 + c1 + c2 + c3;
            int x = s;
#pragma unroll
            for (int d = 1; d < 64; d <<= 1) {
                int y = __shfl_up(x, d, 64);
                if (tid >= d) x += y;
            }
            int ex = x - s;
            Qb[4*tid] = ex; Qb[4*tid+1] = ex + c0;
            Qb[4*tid+2] = ex + c0 + c1; Qb[4*tid+3] = ex + c0 + c1 + c2;
            if (tid == 63) Qb[256] = ex + s;
        }
        __syncthreads();
        const int T = Qb[256];

        float E = *E_p, nu = *nu_p, rho = *rho_p;
        float coeff = E / ((1.f + nu) * (1.f - 2.f * nu));
        float lam = coeff * nu;
        float mu  = coeff * (1.f - 2.f * nu) * 0.5f;

        float d00=0,d01=0,d02=0,d10=0,d11=0,d12=0,d20=0,d21=0,d22=0,vsum=0;
        DECL_VISIT(A_);
        DECL_VISIT(B_);

        bool pending = false, validB = false;
        int s, col = 0, nextV = tid + 1024;
        float v00=0,v01=0,v02=0,v10=0,v11=0,v12=0,v20=0,v21=0,v22=0;

        const int vi0 = tid, vi1 = tid + 512;
        if (vi0 < T) {
            int pk = fetch_entry(entS, Sb, Qb, chunk4S, vi0);
            LOAD_VISIT(A_, pk); DIAG_S(A_); s = 0;
        } else s = 6;
        if (vi1 < T) {
            int pk = fetch_entry(entS, Sb, Qb, chunk4S, vi1);
            LOAD_VISIT(B_, pk); DIAG_S(B_); validB = true;
        }

        auto advanceS = [&]() {
            while (!pending) {
                if (s >= 6 || (s >= 3 && !validB)) {
                    if (nextV >= T) return;
                    int pk = fetch_entry(entS, Sb, Qb, chunk4S, nextV);  // rare tail
                    LOAD_VISIT(B_, pk); DIAG_S(B_);
                    validB = true; nextV += 512; s = 3;
                }
                if (s < 3) { int t_ = s;     int b_ = t_ + (t_ >= A_a ? 1 : 0); PAIR_S(A_, b_); }
                else       { int t_ = s - 3; int b_ = t_ + (t_ >= B_a ? 1 : 0); PAIR_S(B_, b_); }
                ++s; pending = true;
            }
        };

        advanceS();
        int live = __syncthreads_count(pending ? 1 : 0);
        while (live) {
            if (pending) claim[col] = (unsigned short)tid;
            __syncthreads();
            if (pending && claim[col] == (unsigned short)tid) {
                float* p0 = val + 3 * col;
                float* p1 = p0 + n3;
                float* p2 = p1 + n3;
                p0[0]+=v00; p0[1]+=v01; p0[2]+=v02;
                p1[0]+=v10; p1[1]+=v11; p1[2]+=v12;
                p2[0]+=v20; p2[1]+=v21; p2[2]+=v22;
                pending = false;
                advanceS();
            }
            live = __syncthreads_count(pending ? 1 : 0);
        }

        // diagonal reduction
        d00=wave_reduce(d00); d01=wave_reduce(d01); d02=wave_reduce(d02);
        d10=wave_reduce(d10); d11=wave_reduce(d11); d12=wave_reduce(d12);
        d20=wave_reduce(d20); d21=wave_reduce(d21); d22=wave_reduce(d22);
        vsum=wave_reduce(vsum);
        if ((tid & 63) == 0) {
            int w = tid >> 6;
            dred[w*10+0]=d00; dred[w*10+1]=d01; dred[w*10+2]=d02;
            dred[w*10+3]=d10; dred[w*10+4]=d11; dred[w*10+5]=d12;
            dred[w*10+6]=d20; dred[w*10+7]=d21; dred[w*10+8]=d22;
            dred[w*10+9]=vsum;
        }
        __syncthreads();
        if (tid < 10) {
            float t_ = 0.f;
            for (int w = 0; w < 8; ++w) t_ += dred[w*10 + tid];
            dred[80 + tid] = t_;
        }
        __syncthreads();
        if (tid < 9) {
            int i = tid / 3, j = tid - 3 * i;
            val[i * n3 + 3 * r + j] += dred[80 + tid];
        }
        __syncthreads();

        // Ks rows 3r..3r+2: plane i is contiguous -> pure b128 copies
        int q = n3 >> 2;
        for (int k4 = tid; k4 < 3 * q; k4 += 512) {
            int i = (k4 >= q) + (k4 >= 2*q);
            int t4 = k4 - i * q;
            float4 w = ((const float4*)(val + i * n3))[t4];
            ((float4*)(Ks + (size_t)(3*r + i) * n3))[t4] = w;
        }
        // Ms rows: zeros + diagonal
        float diag = rho * 0.25f * dred[89];
        for (int k4 = tid; k4 < 3 * q; k4 += 512) {
            int i = (k4 >= q) + (k4 >= 2*q);
            int t4 = k4 - i * q;
            int dcol = 3*r + i;
            int base = t4 << 2;
            float4 w;
            w.x = (base + 0 == dcol) ? diag : 0.f;
            w.y = (base + 1 == dcol) ? diag : 0.f;
            w.z = (base + 2 == dcol) ? diag : 0.f;
            w.w = (base + 3 == dcol) ? diag : 0.f;
            ((float4*)(Ms + (size_t)(3*r + i) * n3))[t4] = w;
        }
    } else {
        // ================= fluid =================
        const int r = bid - n;
        const int4* elems4 = fe;
        float* val = (float*)smem;                               // 2n (K plane, M plane)
        unsigned short* claim = (unsigned short*)(val + 2 * n);  // n
        int* Sb = (int*)(claim + n);                             // 256
        int* Qb = Sb + 256;                                      // 257
        float* dred = (float*)(Qb + 257);                        // 18

        {
            float4* v = (float4*)val;
            int cnt = (2 * n) >> 2;
            for (int k = tid; k < cnt; k += 512) v[k] = make_float4(0.f,0.f,0.f,0.f);
        }
        if (tid < 256) {
            const int* Pp = PF + (size_t)tid * (n + 1) + r;
            int s0 = Pp[0], e0 = Pp[1];
            Sb[tid] = s0;
            Qb[tid] = e0 - s0;
        }
        __syncthreads();
        if (tid < 64) {
            int c0 = Qb[4*tid], c1 = Qb[4*tid+1], c2 = Qb[4*tid+2], c3 = Qb[4*tid+3];
            int s = c0 + c1 + c2 + c3;
            int x = s;
#pragma unroll
            for (int d = 1; d < 64; d <<= 1) {
                int y = __shfl_up(x, d, 64);
                if (tid >= d) x += y;
            }
            int ex = x - s;
            Qb[4*tid] = ex; Qb[4*tid+1] = ex + c0;
            Qb[4*tid+2] = ex + c0 + c1; Qb[4*tid+3] = ex + c0 + c1 + c2;
            if (tid == 63) Qb[256] = ex + s;
        }
        __syncthreads();
        const int T = Qb[256];

        float dK = 0.f, dM = 0.f;
        DECL_VISIT(A_);
        DECL_VISIT(B_);

        bool pending = false, validB = false;
        int s, col = 0, nextV = tid + 1024;
        float vK = 0.f, vM = 0.f;

        const int vi0 = tid, vi1 = tid + 512;
        if (vi0 < T) {
            int pk = fetch_entry(entF, Sb, Qb, chunk4F, vi0);
            LOAD_VISIT(A_, pk); DIAG_F(A_); s = 0;
        } else s = 6;
        if (vi1 < T) {
            int pk = fetch_entry(entF, Sb, Qb, chunk4F, vi1);
            LOAD_VISIT(B_, pk); DIAG_F(B_); validB = true;
        }

        auto advanceF = [&]() {
            while (!pending) {
                if (s >= 6 || (s >= 3 && !validB)) {
                    if (nextV >= T) return;
                    int pk = fetch_entry(entF, Sb, Qb, chunk4F, nextV);
                    LOAD_VISIT(B_, pk); DIAG_F(B_);
                    validB = true; nextV += 512; s = 3;
                }
                if (s < 3) { int t_ = s;     int b_ = t_ + (t_ >= A_a ? 1 : 0); PAIR_F(A_, b_); }
                else       { int t_ = s - 3; int b_ = t_ + (t_ >= B_a ? 1 : 0); PAIR_F(B_, b_); }
                ++s; pending = true;
            }
        };

        advanceF();
        int live = __syncthreads_count(pending ? 1 : 0);
        while (live) {
            if (pending) claim[col] = (unsigned short)tid;
            __syncthreads();
            if (pending && claim[col] == (unsigned short)tid) {
                val[col]     += vK;
                val[n + col] += vM;
                pending = false;
                advanceF();
            }
            live = __syncthreads_count(pending ? 1 : 0);
        }

        dK = wave_reduce(dK);
        dM = wave_reduce(dM);
        if ((tid & 63) == 0) { int w = tid >> 6; dred[w*2+0] = dK; dred[w*2+1] = dM; }
        __syncthreads();
        if (tid < 2) {
            float t_ = 0.f;
            for (int w = 0; w < 8; ++w) t_ += dred[w*2 + tid];
            dred[16 + tid] = t_;
        }
        __syncthreads();
        if (tid == 0) { val[r] += dred[16]; val[n + r] += dred[17]; }
        __syncthreads();

        size_t rowoff = (size_t)r * n;
        int qf = n >> 2;
        float4* K4 = (float4*)(Kf + rowoff);
        float4* M4 = (float4*)(Mf + rowoff);
        for (int c4 = tid; c4 < qf; c4 += 512) {
            K4[c4] = ((const float4*)val)[c4];
            M4[c4] = ((const float4*)(val + n))[c4];
        }
    }
}

// --------------------------- fallback scatter path ---------------------------
__device__ __forceinline__ void tet_grads_d(const float* __restrict__ nodes,
                                            const int* ni, double g[4][3], double& vol)
{
    double p[4][3];
#pragma unroll
    for (int a = 0; a < 4; ++a) {
        const float* q = nodes + 3ll * ni[a];
        p[a][0] = (double)q[0]; p[a][1] = (double)q[1]; p[a][2] = (double)q[2];
    }
    double r1[3], r2[3], r3[3];
#pragma unroll
    for (int k = 0; k < 3; ++k) {
        r1[k] = p[1][k] - p[0][k];
        r2[k] = p[2][k] - p[0][k];
        r3[k] = p[3][k] - p[0][k];
    }
    double c23[3] = { r2[1]*r3[2]-r2[2]*r3[1], r2[2]*r3[0]-r2[0]*r3[2], r2[0]*r3[1]-r2[1]*r3[0] };
    double det = r1[0]*c23[0] + r1[1]*c23[1] + r1[2]*c23[2];
    double inv = 1.0 / det;
    double c31[3] = { r3[1]*r1[2]-r3[2]*r1[1], r3[2]*r1[0]-r3[0]*r1[2], r3[0]*r1[1]-r3[1]*r1[0] };
    double c12[3] = { r1[1]*r2[2]-r1[2]*r2[1], r1[2]*r2[0]-r1[0]*r2[2], r1[0]*r2[1]-r1[1]*r2[0] };
#pragma unroll
    for (int k = 0; k < 3; ++k) {
        g[1][k] = c23[k]*inv; g[2][k] = c31[k]*inv; g[3][k] = c12[k]*inv;
        g[0][k] = -(g[1][k] + g[2][k] + g[3][k]);
    }
    vol = fabs(det) / 6.0;
}

__global__ void __launch_bounds__(256)
fluid_assemble(const float* __restrict__ nodes, const int* __restrict__ elems,
               float* __restrict__ Kf, float* __restrict__ Mf, int nelem, int n)
{
    int e = blockIdx.x * blockDim.x + threadIdx.x;
    if (e >= nelem) return;
    const int4 nd = *reinterpret_cast<const int4*>(elems + 4ll * e);
    int ni[4] = { nd.x, nd.y, nd.z, nd.w };
    double g[4][3], vol;
    tet_grads_d(nodes, ni, g, vol);
#pragma unroll
    for (int a = 0; a < 4; ++a) {
        long long rowoff = (long long)ni[a] * n;
#pragma unroll
        for (int b = 0; b < 4; ++b) {
            double kv = vol * (g[a][0]*g[b][0] + g[a][1]*g[b][1] + g[a][2]*g[b][2]);
            double mv = vol * (a == b ? 0.3 : 0.1);
            atomicAdd(Kf + rowoff + ni[b], (float)kv);
            atomicAdd(Mf + rowoff + ni[b], (float)mv);
        }
    }
}

__global__ void __launch_bounds__(256)
solid_assemble(const float* __restrict__ nodes, const int* __restrict__ elems,
               float* __restrict__ Ks, float* __restrict__ Ms,
               const float* __restrict__ E_p, const float* __restrict__ nu_p,
               const float* __restrict__ rho_p, int nelem, int n3)
{
    int e = blockIdx.x * blockDim.x + threadIdx.x;
    if (e >= nelem) return;
    double E = (double)*E_p, nu = (double)*nu_p, rho = (double)*rho_p;
    double coeff = E / ((1.0 + nu) * (1.0 - 2.0 * nu));
    double lam = coeff * nu, mu = coeff * (1.0 - 2.0 * nu) * 0.5;
    const int4 nd = *reinterpret_cast<const int4*>(elems + 4ll * e);
    int ni[4] = { nd.x, nd.y, nd.z, nd.w };
    double g[4][3], vol;
    tet_grads_d(nodes, ni, g, vol);
    double lv = lam * vol, mv = mu * vol;
#pragma unroll
    for (int a = 0; a < 4; ++a) {
        long long row0 = 3ll * ni[a];
#pragma unroll
        for (int b = 0; b < 4; ++b) {
            long long col0 = 3ll * ni[b];
            double gg = g[a][0]*g[b][0] + g[a][1]*g[b][1] + g[a][2]*g[b][2];
#pragma unroll
            for (int i = 0; i < 3; ++i) {
                float* rowp = Ks + (row0 + i) * (long long)n3 + col0;
#pragma unroll
                for (int j = 0; j < 3; ++j) {
                    double val = lv * g[a][i] * g[b][j] + mv * g[a][j] * g[b][i];
                    if (i == j) val += mv * gg;
                    atomicAdd(rowp + j, (float)val);
                }
            }
        }
        float mval = (float)(rho * vol * 0.25);
#pragma unroll
        for (int i = 0; i < 3; ++i) {
            long long d = row0 + i;
            atomicAdd(Ms + d * (long long)n3 + d, mval);
        }
    }
}

// ---------------------------------------------------------------------------
extern "C" void kernel_launch(void* const* d_in, const int* in_sizes, int n_in,
                              void* d_out, int out_size, void* d_ws, size_t ws_size,
                              hipStream_t stream)
{
    const float* nodes = (const float*)d_in[0];
    const int*   fe    = (const int*)d_in[1];
    const int*   se    = (const int*)d_in[2];
    const float* E_p   = (const float*)d_in[3];
    const float* nu_p  = (const float*)d_in[4];
    const float* rho_p = (const float*)d_in[5];

    const int n  = in_sizes[0] / 3;
    const int nf = in_sizes[1] / 4;
    const int ns = in_sizes[2] / 4;
    const int n3 = 3 * n;

    float* out = (float*)d_out;
    float* Kf = out;
    float* Mf = Kf + (size_t)n * n;
    float* Ks = Mf + (size_t)n * n;
    float* Ms = Ks + (size_t)n3 * n3;

    const int chunkF = (nf + G_PART - 1) / G_PART;
    const int chunkS = (ns + G_PART - 1) / G_PART;

    size_t pos = 0;
    auto take = [&](size_t bytes) {
        size_t p = pos;
        pos = (pos + bytes + 255) & ~(size_t)255;
        return p;
    };
    size_t entF_o = take((size_t)4 * chunkF * G_PART * 4);
    size_t entS_o = take((size_t)4 * chunkS * G_PART * 4);
    size_t PF_o   = take((size_t)G_PART * (n + 1) * 4);
    size_t PS_o   = take((size_t)G_PART * (n + 1) * 4);

    size_t gatherLds = (size_t)9 * n * 4 + (size_t)n * 2 + (256 + 257) * 4 + 96 * 4;
    size_t indexLds  = (size_t)(n + 256) * 4;
    bool gather_ok = (pos <= ws_size) && ((n & 3) == 0) && (n <= 65535) &&
                     (gatherLds <= 160 * 1024) && (indexLds <= 64 * 1024);

    const int bs = 256;

    if (!gather_ok) {
        hipMemsetAsync(d_out, 0, (size_t)out_size * sizeof(float), stream);
        fluid_assemble<<<(nf + bs - 1) / bs, bs, 0, stream>>>(nodes, fe, Kf, Mf, nf, n);
        solid_assemble<<<(ns + bs - 1) / bs, bs, 0, stream>>>(nodes, se, Ks, Ms,
                                                              E_p, nu_p, rho_p, ns, n3);
        return;
    }

    char* ws = (char*)d_ws;
    int* entF = (int*)(ws + entF_o);
    int* entS = (int*)(ws + entS_o);
    int* PF   = (int*)(ws + PF_o);
    int* PS   = (int*)(ws + PS_o);

    const int4* fe4 = (const int4*)fe;
    const int4* se4 = (const int4*)se;

    index_build<<<2 * G_PART, bs, indexLds, stream>>>(fe4, se4, entF, entS, PF, PS,
                                                      nf, ns, n, chunkF, chunkS);
    fused_gather<<<2 * n, 512, gatherLds, stream>>>(entF, PF, entS, PS,
                                                    fe4, se4, nodes,
                                                    Kf, Mf, Ks, Ms,
                                                    E_p, nu_p, rho_p, n, n3,
                                                    4 * chunkF, 4 * chunkS);
}